// Round 12
// baseline (405.037 us; speedup 1.0000x reference)
//
#include <hip/hip_runtime.h>

#define H96 96

typedef __attribute__((ext_vector_type(8))) short bf16x8_t;
typedef __attribute__((ext_vector_type(4))) float f32x4_t;
typedef __attribute__((ext_vector_type(8))) _Float16 half8_t;

// ---------------- degrees: node-range-partitioned LDS histograms (r11, -45us) ----------------
// ZERO global atomics (device-scope atomics write through to HBM ~32B each).
#define NRANGE 8
#define NCHUNK 64

__global__ __launch_bounds__(256) void hist2_kernel(const int* __restrict__ src,
                                                    const int* __restrict__ dst,
                                                    unsigned short* __restrict__ parts,
                                                    int E, int RS, int ecpc) {
    extern __shared__ int h[];            // [2][RS] ints
    int r = blockIdx.x >> 6;              // node range
    int c = blockIdx.x & 63;              // edge chunk
    int lo = r * RS;
    for (int i = threadIdx.x; i < 2 * RS; i += 256) h[i] = 0;
    __syncthreads();
    int e0 = c * ecpc;
    int e1 = min(e0 + ecpc, E);
    for (int base = e0 + threadIdx.x * 4; base < e1; base += 1024) {
        int cnt = min(4, e1 - base);
        if (cnt == 4) {
            int4 sv = *(const int4*)(src + base);
            int4 dv = *(const int4*)(dst + base);
            int a;
            a = sv.x - lo; if ((unsigned)a < (unsigned)RS) atomicAdd(&h[a], 1);
            a = sv.y - lo; if ((unsigned)a < (unsigned)RS) atomicAdd(&h[a], 1);
            a = sv.z - lo; if ((unsigned)a < (unsigned)RS) atomicAdd(&h[a], 1);
            a = sv.w - lo; if ((unsigned)a < (unsigned)RS) atomicAdd(&h[a], 1);
            a = dv.x - lo; if ((unsigned)a < (unsigned)RS) atomicAdd(&h[RS + a], 1);
            a = dv.y - lo; if ((unsigned)a < (unsigned)RS) atomicAdd(&h[RS + a], 1);
            a = dv.z - lo; if ((unsigned)a < (unsigned)RS) atomicAdd(&h[RS + a], 1);
            a = dv.w - lo; if ((unsigned)a < (unsigned)RS) atomicAdd(&h[RS + a], 1);
        } else {
            for (int k = 0; k < cnt; k++) {
                int a = src[base + k] - lo;
                if ((unsigned)a < (unsigned)RS) atomicAdd(&h[a], 1);
                a = dst[base + k] - lo;
                if ((unsigned)a < (unsigned)RS) atomicAdd(&h[RS + a], 1);
            }
        }
    }
    __syncthreads();
    // parts layout: [range][p(src/dst)][chunk][RS] ushort
    unsigned short* po = parts + ((size_t)(r * 2 + 0) * NCHUNK + c) * RS;
    unsigned short* pi = parts + ((size_t)(r * 2 + 1) * NCHUNK + c) * RS;
    for (int i = threadIdx.x; i < RS; i += 256) {
        po[i] = (unsigned short)h[i];
        pi[i] = (unsigned short)h[RS + i];
    }
}

// reduce partials -> degrees, norms, iperm (fused)
__global__ void degred_kernel(const unsigned short* __restrict__ parts,
                              const int* __restrict__ perm,
                              int* __restrict__ deg_in, int* __restrict__ iperm,
                              float* __restrict__ no, float* __restrict__ ni,
                              int N, int RS) {
    int i = blockIdx.x * 256 + threadIdx.x;
    if (i >= N) return;
    int r = i / RS, idx = i - r * RS;
    const unsigned short* po = parts + ((size_t)(r * 2 + 0) * NCHUNK) * RS + idx;
    const unsigned short* pi = parts + ((size_t)(r * 2 + 1) * NCHUNK) * RS + idx;
    int so = 0, si = 0;
#pragma unroll
    for (int c = 0; c < NCHUNK; c++) {
        so += po[(size_t)c * RS];
        si += pi[(size_t)c * RS];
    }
    deg_in[i] = si;
    no[i] = rsqrtf(fmaxf((float)so, 1.0f));
    ni[i] = rsqrtf(fmaxf((float)si, 1.0f));
    iperm[perm[i]] = i;
}

// r12: exact per-(chunk,node) CSR base positions from hist2 partials:
// cpre[c][i] = row_start[i] + sum_{c'<c} parts[r][1][c'][i].
__global__ void chunkpre_kernel(const unsigned short* __restrict__ parts,
                                const int* __restrict__ row_start,
                                int* __restrict__ cpre, int N, int RS) {
    int i = blockIdx.x * 256 + threadIdx.x;
    if (i >= N) return;
    int r = i / RS, idx = i - r * RS;
    const unsigned short* pi = parts + ((size_t)(r * 2 + 1) * NCHUNK) * RS + idx;
    int run = row_start[i];
#pragma unroll
    for (int c = 0; c < NCHUNK; c++) {
        cpre[(size_t)c * N + i] = run;
        run += pi[(size_t)c * RS];
    }
}

// ---------------- generic exclusive scan ----------------
__global__ void scanA_kernel(const int* __restrict__ in, int* __restrict__ pre,
                             int* __restrict__ bsums, int n) {
    __shared__ int s[256];
    int i = blockIdx.x * 256 + threadIdx.x;
    int v = (i < n) ? in[i] : 0;
    s[threadIdx.x] = v;
    __syncthreads();
    for (int off = 1; off < 256; off <<= 1) {
        int t = (threadIdx.x >= off) ? s[threadIdx.x - off] : 0;
        __syncthreads();
        s[threadIdx.x] += t;
        __syncthreads();
    }
    if (i < n) pre[i] = s[threadIdx.x] - v;
    if (threadIdx.x == 255) bsums[blockIdx.x] = s[255];
}

__global__ void scanB_kernel(int* __restrict__ bsums, int nb) {
    __shared__ int s[256];
    int v = (threadIdx.x < nb) ? bsums[threadIdx.x] : 0;
    s[threadIdx.x] = v;
    __syncthreads();
    for (int off = 1; off < 256; off <<= 1) {
        int t = (threadIdx.x >= off) ? s[threadIdx.x - off] : 0;
        __syncthreads();
        s[threadIdx.x] += t;
        __syncthreads();
    }
    if (threadIdx.x < nb) bsums[threadIdx.x] = s[threadIdx.x] - v;
}

__global__ void rowfin_kernel(const int* __restrict__ pre, const int* __restrict__ bsums,
                              int* __restrict__ row_start, int N, int E) {
    int i = blockIdx.x * 256 + threadIdx.x;
    if (i < N) row_start[i] = pre[i] + bsums[blockIdx.x];
    if (i == 0) row_start[N] = E;
}

// r12 CSR scatter: range x chunk blocks, LDS cursors seeded from cpre.
// ZERO global atomics (was 800K cursor atomics = ~25MB HBM write-through).
__global__ __launch_bounds__(256) void scatter8_kernel(const int* __restrict__ src,
                                                       const int* __restrict__ dst,
                                                       const float* __restrict__ norm_out,
                                                       const int* __restrict__ cpre,
                                                       int2* __restrict__ edge2,
                                                       int E, int N, int RS, int ecpc) {
    extern __shared__ int cur[];          // RS ints
    int r = blockIdx.x >> 6, c = blockIdx.x & 63;
    int lo = r * RS;
    int len = min(RS, N - lo);
    for (int i = threadIdx.x; i < len; i += 256)
        cur[i] = cpre[(size_t)c * N + lo + i];
    __syncthreads();
    int e0 = c * ecpc, e1 = min(e0 + ecpc, E);
    for (int e = e0 + threadIdx.x; e < e1; e += 256) {
        int d = dst[e] - lo;
        if ((unsigned)d < (unsigned)len) {
            int s = src[e];
            int p = atomicAdd(&cur[d], 1);
            edge2[p] = make_int2(s, __float_as_int(norm_out[s]));
        }
    }
}

// ---------------- low-contention counting sort by deg_in ----------------
__global__ void histblk_kernel(const int* __restrict__ deg, int* __restrict__ hb,
                               int N, int nb) {
    __shared__ int h[256];
    h[threadIdx.x] = 0;
    __syncthreads();
    int i = blockIdx.x * 256 + threadIdx.x;
    if (i < N) atomicAdd(&h[min(deg[i], 255)], 1);
    __syncthreads();
    hb[threadIdx.x * nb + blockIdx.x] = h[threadIdx.x];
}

__global__ void place2_kernel(const int* __restrict__ deg, const int* __restrict__ hpre,
                              const int* __restrict__ bsums, int* __restrict__ order,
                              int N, int nb) {
    __shared__ int cur[256];
    int idx = threadIdx.x * nb + blockIdx.x;
    cur[threadIdx.x] = hpre[idx] + bsums[idx >> 8];
    __syncthreads();
    int i = blockIdx.x * 256 + threadIdx.x;
    if (i < N) {
        int b = min(deg[i], 255);
        int p = atomicAdd(&cur[b], 1);
        order[p] = i;
    }
}

// ---------------- bf16 hi/lo split helpers ----------------
__device__ __forceinline__ void f2bf2(float v, unsigned short& h, unsigned short& l) {
    unsigned int b = __float_as_uint(v);
    unsigned short hh = (unsigned short)((b + 0x7FFFu + ((b >> 16) & 1u)) >> 16);
    float fh = __uint_as_float(((unsigned int)hh) << 16);
    float r = v - fh;
    unsigned int rb = __float_as_uint(r);
    unsigned short ll = (unsigned short)((rb + 0x7FFFu + ((rb >> 16) & 1u)) >> 16);
    h = hh; l = ll;
}

__device__ __forceinline__ void cvt8(const float f[8], bf16x8_t& ah, bf16x8_t& al) {
    union { unsigned int u[4]; bf16x8_t v; } H, L;
#pragma unroll
    for (int i = 0; i < 4; i++) {
        float v0 = f[2 * i], v1 = f[2 * i + 1];
        unsigned int b0 = __float_as_uint(v0);
        unsigned int b1 = __float_as_uint(v1);
        unsigned int m0 = b0 & 0xFFFF0000u;
        unsigned int m1 = b1 & 0xFFFF0000u;
        float r0 = v0 - __uint_as_float(m0);
        float r1 = v1 - __uint_as_float(m1);
        H.u[i] = (b0 >> 16) | m1;
        L.u[i] = (__float_as_uint(r0) >> 16) | (__float_as_uint(r1) & 0xFFFF0000u);
    }
    ah = H.v; al = L.v;
}

// fused weights prep
__global__ void weights_prep(const float* __restrict__ W1, const float* __restrict__ W2,
                             const float* __restrict__ Wm, const float* __restrict__ bm,
                             unsigned short* __restrict__ w1h, unsigned short* __restrict__ w1l,
                             unsigned short* __restrict__ w2h, unsigned short* __restrict__ w2l,
                             float* __restrict__ wsum, float* __restrict__ bsum,
                             int F, int KP1) {
    int idx = blockIdx.x * 256 + threadIdx.x;
    int z1 = 96 * KP1, z2 = z1 + 96 * 96;
    if (idx < z1) {
        int n = idx / KP1, k = idx - n * KP1;
        float v = (k < F) ? W1[(size_t)k * 96 + n] : 0.f;
        unsigned short h, l;
        f2bf2(v, h, l);
        w1h[idx] = h; w1l[idx] = l;
    } else if (idx < z2) {
        int t = idx - z1;
        int n = t / 96, k = t - n * 96;
        float v = W2[(size_t)k * 96 + n];
        unsigned short h, l;
        f2bf2(v, h, l);
        w2h[t] = h; w2l[t] = l;
    } else if (idx < z2 + 96) {
        int c = idx - z2;
        float s = 0.f;
        for (int j = 0; j < 96; j++) s += Wm[c * 96 + j];
        wsum[c] = s;
    } else if (idx == z2 + 96) {
        float s = 0.f;
        for (int j = 0; j < 96; j++) s += bm[j];
        bsum[0] = s;
    }
}

#define GBK 32

__device__ __forceinline__ void gload_lds16(const void* g, void* l) {
    __builtin_amdgcn_global_load_lds(
        (const __attribute__((address_space(1))) unsigned int*)g,
        (__attribute__((address_space(3))) unsigned int*)l, 16, 0, 0);
}

// ---------------- async-LDS-B bf16x3 MFMA GEMM, BM=32 (r12) ----------------
// r12 change vs r11: BM 64->32. Grid doubles (1564 blocks -> 6.1 blocks/CU vs
// 3.05 at capacity 6) to fix the stable Occ=23% latency limit. Staging and
// sync skeleton UNCHANGED (same 96x32 B slab, same per-wave ledger: 3 stage +
// 2 A loads/iter, vmcnt(5)). Wave w: rows (w>>1)*16, ct half (w&1)*3 (acc 12
// VGPR). Pair-write epilogue unchanged (ct offset by half).
__global__ __launch_bounds__(256, 6) void gemm_mfma(const void* __restrict__ Av,
                                                    const unsigned short* __restrict__ Bth,
                                                    const unsigned short* __restrict__ Btl,
                                                    _Float16* __restrict__ C16,
                                                    const int* __restrict__ ipermArr,
                                                    int M, int K, int KP) {
    // [buf][part][row][slot][8 halfs] = 2*2*96*4*8 ush = 24576 B
    __shared__ alignas(16) unsigned short Bs[2][2][96][4][8];
    int tid = threadIdx.x;
    int wid = tid >> 6, lane = tid & 63;
    int q = lane >> 4, mn = lane & 15;
    int rg = wid >> 1, ch = wid & 1;
    int row0 = blockIdx.x * 32 + rg * 16;
    int arow = min(row0 + mn, M - 1);   // clamp (no predication): uniform VMEM count
    int nk = (K + GBK - 1) / GBK;

    const float* A32 = (const float*)Av;

    const unsigned short* gsrc[3];
    int lbase[3];
#pragma unroll
    for (int i = 0; i < 3; i++) {
        int c = wid * 192 + i * 64 + lane;
        int part = (c >= 384) ? 1 : 0;
        int rem = c - part * 384;
        int row = rem >> 2, slot = rem & 3;
        int kc = slot ^ ((row >> 1) & 3);
        gsrc[i] = (part ? Btl : Bth) + (size_t)row * KP + kc * 8;
        lbase[i] = (wid * 192 + i * 64) * 8;   // wave-uniform chunk-linear dest
    }

    auto stage = [&](int t, int buf) {
#pragma unroll
        for (int i = 0; i < 3; i++)
            gload_lds16(gsrc[i] + (size_t)t * GBK, &Bs[buf][0][0][0][0] + lbase[i]);
    };

    auto loadA = [&](int t, float* f) {
        int gk = t * GBK + q * 8;
        if (gk + 8 <= K) {
            float4 v0 = *(const float4*)(A32 + (size_t)arow * K + gk);
            float4 v1 = *(const float4*)(A32 + (size_t)arow * K + gk + 4);
            f[0] = v0.x; f[1] = v0.y; f[2] = v0.z; f[3] = v0.w;
            f[4] = v1.x; f[5] = v1.y; f[6] = v1.z; f[7] = v1.w;
        } else {
#pragma unroll
            for (int c = 0; c < 8; c++)
                f[c] = (gk + c < K) ? A32[(size_t)arow * K + gk + c] : 0.f;
        }
    };

    f32x4_t acc[3] = {};
    float f[8], fn[8];

    stage(0, 0);
    loadA(0, f);

    int slotR = q ^ ((mn >> 1) & 3);

    for (int t = 0; t < nk; t++) {
        int tn = (t + 1 < nk) ? t + 1 : nk - 1;   // clamped: uniform issue count
        stage(tn, (t + 1) & 1);
        loadA(tn, fn);
        asm volatile("s_waitcnt vmcnt(5)" ::: "memory");
        __builtin_amdgcn_sched_barrier(0);
        __builtin_amdgcn_s_barrier();

        bf16x8_t ah, al;
        cvt8(f, ah, al);

        const unsigned short* bp = &Bs[t & 1][0][0][0][0] + mn * 32 + slotR * 8 + ch * 1536;
#pragma unroll
        for (int ct2 = 0; ct2 < 3; ct2++) {
            bf16x8_t bh = *(const bf16x8_t*)(bp + ct2 * 512);
            bf16x8_t bl = *(const bf16x8_t*)(bp + 3072 + ct2 * 512);
            acc[ct2] = __builtin_amdgcn_mfma_f32_16x16x32_bf16(ah, bh, acc[ct2], 0, 0, 0);
            acc[ct2] = __builtin_amdgcn_mfma_f32_16x16x32_bf16(ah, bl, acc[ct2], 0, 0, 0);
            acc[ct2] = __builtin_amdgcn_mfma_f32_16x16x32_bf16(al, bh, acc[ct2], 0, 0, 0);
        }
        asm volatile("s_waitcnt lgkmcnt(0)" ::: "memory");
        __builtin_amdgcn_sched_barrier(0);
        __builtin_amdgcn_s_barrier();

#pragma unroll
        for (int c = 0; c < 8; c++) f[c] = fn[c];
    }

    // drain outstanding LDS-destined staging loads before exit
    asm volatile("s_waitcnt vmcnt(0)" ::: "memory");
    __builtin_amdgcn_sched_barrier(0);

#pragma unroll
    for (int reg = 0; reg < 4; reg++) {
        int gr = row0 + q * 4 + reg;
        if (gr < M) {
            int ip = ipermArr[gr];
#pragma unroll
            for (int ct2 = 0; ct2 < 3; ct2++) {
                int col = (ch * 3 + ct2) * 16 + mn;
                _Float16 v = (_Float16)acc[ct2][reg];
                C16[(size_t)gr * 192 + col] = v;        // ypair[gr][0]
                C16[(size_t)ip * 192 + 96 + col] = v;   // ypair[iperm[gr]][1]
            }
        }
    }
}

// ---------------- gemm_small: K=96 whole-B-in-LDS, single-barrier (r10, passed) ----------------
__global__ __launch_bounds__(256, 4) void gemm_small(const _Float16* __restrict__ A16,
                                                     const unsigned short* __restrict__ Bth,
                                                     const unsigned short* __restrict__ Btl,
                                                     _Float16* __restrict__ C16,
                                                     int M) {
    __shared__ alignas(16) unsigned short Bs[3][2][96][4][8];   // 36864 B
    const int K = 96;
    int tid = threadIdx.x;
    int wid = tid >> 6, lane = tid & 63;
    int q = lane >> 4, mn = lane & 15;
    int row0 = blockIdx.x * 64 + wid * 16;
    int arow = min(row0 + mn, M - 1);

    const unsigned short* gsrc[3];
    int lbase[3];
#pragma unroll
    for (int i = 0; i < 3; i++) {
        int c = wid * 192 + i * 64 + lane;
        int part = (c >= 384) ? 1 : 0;
        int rem = c - part * 384;
        int row = rem >> 2, slot = rem & 3;
        int kc = slot ^ ((row >> 1) & 3);
        gsrc[i] = (part ? Btl : Bth) + (size_t)row * K + kc * 8;
        lbase[i] = (wid * 192 + i * 64) * 8;
    }

#pragma unroll
    for (int t = 0; t < 3; t++)
#pragma unroll
        for (int i = 0; i < 3; i++)
            gload_lds16(gsrc[i] + (size_t)t * GBK, &Bs[t][0][0][0][0] + lbase[i]);

    uint4 ra0 = *(const uint4*)(A16 + (size_t)arow * K + 0 * GBK + q * 8);
    uint4 ra1 = *(const uint4*)(A16 + (size_t)arow * K + 1 * GBK + q * 8);
    uint4 ra2 = *(const uint4*)(A16 + (size_t)arow * K + 2 * GBK + q * 8);

    asm volatile("s_waitcnt vmcnt(0)" ::: "memory");
    __builtin_amdgcn_sched_barrier(0);
    __builtin_amdgcn_s_barrier();

    f32x4_t acc[6] = {};
    int slotR = q ^ ((mn >> 1) & 3);

    auto step = [&](int t, const uint4& raw) {
        float f[8];
        const _Float16* hp = (const _Float16*)&raw;
#pragma unroll
        for (int c = 0; c < 8; c++) f[c] = (float)hp[c];
        bf16x8_t ah, al;
        cvt8(f, ah, al);
        const unsigned short* bp = &Bs[t][0][0][0][0] + mn * 32 + slotR * 8;
#pragma unroll
        for (int ct = 0; ct < 6; ct++) {
            bf16x8_t bh = *(const bf16x8_t*)(bp + ct * 512);
            bf16x8_t bl = *(const bf16x8_t*)(bp + 3072 + ct * 512);
            acc[ct] = __builtin_amdgcn_mfma_f32_16x16x32_bf16(ah, bh, acc[ct], 0, 0, 0);
            acc[ct] = __builtin_amdgcn_mfma_f32_16x16x32_bf16(ah, bl, acc[ct], 0, 0, 0);
            acc[ct] = __builtin_amdgcn_mfma_f32_16x16x32_bf16(al, bh, acc[ct], 0, 0, 0);
        }
    };

    step(0, ra0);
    step(1, ra1);
    step(2, ra2);

#pragma unroll
    for (int reg = 0; reg < 4; reg++) {
        int gr = row0 + q * 4 + reg;
        if (gr < M) {
#pragma unroll
            for (int ct = 0; ct < 6; ct++)
                C16[(size_t)gr * H96 + ct * 16 + mn] = (_Float16)acc[ct][reg];
        }
    }
}

// ---------------- helpers ----------------
__device__ __forceinline__ void fmah8(float4& a, float4& b, float s, half8_t v) {
    a.x = fmaf(s, (float)v[0], a.x); a.y = fmaf(s, (float)v[1], a.y);
    a.z = fmaf(s, (float)v[2], a.z); a.w = fmaf(s, (float)v[3], a.w);
    b.x = fmaf(s, (float)v[4], b.x); b.y = fmaf(s, (float)v[5], b.y);
    b.z = fmaf(s, (float)v[6], b.z); b.w = fmaf(s, (float)v[7], b.w);
}

__device__ __forceinline__ float4 prelu4(float4 acc, float ni, float4 b, float4 a) {
    float4 h;
    h.x = fmaf(acc.x, ni, b.x); h.x = (h.x >= 0.f) ? h.x : a.x * h.x;
    h.y = fmaf(acc.y, ni, b.y); h.y = (h.y >= 0.f) ? h.y : a.y * h.y;
    h.z = fmaf(acc.z, ni, b.z); h.z = (h.z >= 0.f) ? h.z : a.z * h.z;
    h.w = fmaf(acc.w, ni, b.w); h.w = (h.w >= 0.f) ? h.w : a.w * h.w;
    return h;
}

// ---------------- layer-1 dual-view SpMM over PAIRED fp16 table ----------------
__global__ __launch_bounds__(384) void spmm1_dual(
        const half8_t* __restrict__ yp, const int* __restrict__ row_start,
        const int2* __restrict__ edge2, const int* __restrict__ order,
        const float* __restrict__ norm_out, const float* __restrict__ norm_in,
        const float* __restrict__ b1, const float* __restrict__ a1,
        half8_t* __restrict__ hpair, int N) {
    int g = blockIdx.x * 32 + threadIdx.y;
    if (g >= N) return;
    int d = order[g];
    int tx = threadIdx.x;
    int beg = row_start[d], end = row_start[d + 1];
    const half8_t* yt = yp + tx;
    float4 a1a = {0,0,0,0}, a1b = {0,0,0,0}, a2a = {0,0,0,0}, a2b = {0,0,0,0};
    int j = beg;
    for (; j + 8 <= end; j += 8) {
        int2 e[8];
#pragma unroll
        for (int q = 0; q < 8; q++) e[q] = edge2[j + q];
        half8_t u[8], w[8];
#pragma unroll
        for (int q = 0; q < 8; q++) u[q] = yt[(size_t)e[q].x * 24];
#pragma unroll
        for (int q = 0; q < 8; q++) w[q] = yt[(size_t)e[q].x * 24 + 12];
#pragma unroll
        for (int q = 0; q < 8; q++) {
            float n = __int_as_float(e[q].y);
            fmah8(a1a, a1b, n, u[q]);
            fmah8(a2a, a2b, n, w[q]);
        }
    }
    for (; j < end; j++) {
        int2 e = edge2[j];
        float n = __int_as_float(e.y);
        fmah8(a1a, a1b, n, yt[(size_t)e.x * 24]);
        fmah8(a2a, a2b, n, yt[(size_t)e.x * 24 + 12]);
    }
    float ni = norm_in[d], no = norm_out[d];
    float4 bb0 = ((const float4*)b1)[tx * 2], bb1 = ((const float4*)b1)[tx * 2 + 1];
    float4 aa0 = ((const float4*)a1)[tx * 2], aa1 = ((const float4*)a1)[tx * 2 + 1];
    float4 r1a = prelu4(a1a, ni, bb0, aa0), r1b = prelu4(a1b, ni, bb1, aa1);
    float4 r2a = prelu4(a2a, ni, bb0, aa0), r2b = prelu4(a2b, ni, bb1, aa1);
    half8_t o1, o2;
    o1[0] = (_Float16)(r1a.x * no); o1[1] = (_Float16)(r1a.y * no);
    o1[2] = (_Float16)(r1a.z * no); o1[3] = (_Float16)(r1a.w * no);
    o1[4] = (_Float16)(r1b.x * no); o1[5] = (_Float16)(r1b.y * no);
    o1[6] = (_Float16)(r1b.z * no); o1[7] = (_Float16)(r1b.w * no);
    o2[0] = (_Float16)(r2a.x * no); o2[1] = (_Float16)(r2a.y * no);
    o2[2] = (_Float16)(r2a.z * no); o2[3] = (_Float16)(r2a.w * no);
    o2[4] = (_Float16)(r2b.x * no); o2[5] = (_Float16)(r2b.y * no);
    o2[6] = (_Float16)(r2b.z * no); o2[7] = (_Float16)(r2b.w * no);
    hpair[(size_t)d * 24 + tx] = o1;
    hpair[(size_t)d * 24 + 12 + tx] = o2;
}

// ---------------- layer-2 dual-view SpMM over node-interleaved t table ----------------
__global__ __launch_bounds__(384) void spmm2_dual(
        const half8_t* __restrict__ th,
        const int* __restrict__ row_start, const int2* __restrict__ edge2,
        const int* __restrict__ order, const float* __restrict__ norm_in,
        const float* __restrict__ b2, const float* __restrict__ a2,
        const float* __restrict__ wsum, const float* __restrict__ bsum,
        float* __restrict__ outp, int N) {
    int g = blockIdx.x * 32 + threadIdx.y;
    int tx = threadIdx.x;
    int ty = threadIdx.y;
    bool valid = (g < N);
    int d = valid ? order[g] : 0;
    int beg = 0, end = 0;
    if (valid) { beg = row_start[d]; end = row_start[d + 1]; }
    const half8_t* t1 = th + tx;
    float4 a1a = {0,0,0,0}, a1b = {0,0,0,0}, a2a = {0,0,0,0}, a2b = {0,0,0,0};
    int j = beg;
    for (; j + 8 <= end; j += 8) {
        int s[8];
#pragma unroll
        for (int q = 0; q < 8; q++) s[q] = edge2[j + q].x;
        half8_t u[8], w[8];
#pragma unroll
        for (int q = 0; q < 8; q++) u[q] = t1[(size_t)s[q] * 24];
#pragma unroll
        for (int q = 0; q < 8; q++) w[q] = t1[(size_t)s[q] * 24 + 12];
#pragma unroll
        for (int q = 0; q < 8; q++) {
            fmah8(a1a, a1b, 1.f, u[q]);
            fmah8(a2a, a2b, 1.f, w[q]);
        }
    }
    for (; j < end; j++) {
        int s = edge2[j].x;
        fmah8(a1a, a1b, 1.f, t1[(size_t)s * 24]);
        fmah8(a2a, a2b, 1.f, t1[(size_t)s * 24 + 12]);
    }
    float ni = valid ? norm_in[d] : 0.f;
    float4 bb0 = ((const float4*)b2)[tx * 2], bb1 = ((const float4*)b2)[tx * 2 + 1];
    float4 aa0 = ((const float4*)a2)[tx * 2], aa1 = ((const float4*)a2)[tx * 2 + 1];
    float4 wv0 = ((const float4*)wsum)[tx * 2], wv1 = ((const float4*)wsum)[tx * 2 + 1];
    float4 r1a = prelu4(a1a, ni, bb0, aa0), r1b = prelu4(a1b, ni, bb1, aa1);
    float4 r2a = prelu4(a2a, ni, bb0, aa0), r2b = prelu4(a2b, ni, bb1, aa1);
    float p1 = r1a.x * wv0.x + r1a.y * wv0.y + r1a.z * wv0.z + r1a.w * wv0.w
             + r1b.x * wv1.x + r1b.y * wv1.y + r1b.z * wv1.z + r1b.w * wv1.w;
    float p2 = r2a.x * wv0.x + r2a.y * wv0.y + r2a.z * wv0.z + r2a.w * wv0.w
             + r2b.x * wv1.x + r2b.y * wv1.y + r2b.z * wv1.z + r2b.w * wv1.w;
    __shared__ float red1[32][12];
    __shared__ float red2[32][12];
    red1[ty][tx] = p1;
    red2[ty][tx] = p2;
    __syncthreads();
    if (tx == 0 && valid) {
        float s1 = 0.f, s2 = 0.f;
#pragma unroll
        for (int k = 0; k < 12; k++) { s1 += red1[ty][k]; s2 += red2[ty][k]; }
        outp[d] = s1 + bsum[0];
        outp[N + d] = s2 + bsum[0];
    }
}

extern "C" void kernel_launch(void* const* d_in, const int* in_sizes, int n_in,
                              void* d_out, int out_size, void* d_ws, size_t ws_size,
                              hipStream_t stream) {
    const float* x    = (const float*)d_in[0];
    const int*   src  = (const int*)d_in[1];
    const int*   dst  = (const int*)d_in[2];
    const int*   perm = (const int*)d_in[3];
    const float* W1   = (const float*)d_in[4];
    const float* b1   = (const float*)d_in[5];
    const float* a1   = (const float*)d_in[6];
    const float* W2   = (const float*)d_in[7];
    const float* b2   = (const float*)d_in[8];
    const float* a2   = (const float*)d_in[9];
    const float* Wm   = (const float*)d_in[10];
    const float* bm   = (const float*)d_in[11];
    float* out = (float*)d_out;

    int E = in_sizes[1];
    int N = in_sizes[3];
    int F = in_sizes[0] / N;               // 500
    int KP1 = ((F + GBK - 1) / GBK) * GBK; // 512

    size_t NP = ((size_t)N + 256) & ~(size_t)255;
    size_t EP = ((size_t)E + 255) & ~(size_t)255;
    int nb = (N + 255) / 256;
    size_t HB = ((size_t)256 * nb + 255) & ~(size_t)255;

    int* iperm     = (int*)d_ws;          // NP
    int* deg_in    = iperm + NP;          // NP
    int* pre       = deg_in + NP;         // NP
    int* row_start = pre + NP;            // NP
    int* cursor    = row_start + NP;      // NP (unused slot, kept for layout)
    int* order     = cursor + NP;         // NP
    int* bsums     = order + NP;          // 256
    int* hb        = bsums + 256;         // HB
    int* hpre      = hb + HB;             // HB
    int2* edge2    = (int2*)(hpre + HB);  // EP int2 (6.4MB)
    float* norm_out = (float*)(edge2 + EP);    // NP
    float* norm_in  = norm_out + NP;           // NP
    float* wsum     = norm_in + NP;            // 128
    float* bsum     = wsum + 128;              // 128
    unsigned short* w1th = (unsigned short*)(bsum + 128); // 96*KP1 pad 49664
    unsigned short* w1tl = w1th + 49664;
    unsigned short* w2th = w1tl + 49664;                  // 96*96 pad 9728
    unsigned short* w2tl = w2th + 9728;
    // fp16 scratch: fpA = ypair then th (aliased; ypair dead after spmm1),
    // fpB = hpair.
    _Float16* fpA = (_Float16*)(w2tl + 9728);            // N*192 + 256
    _Float16* fpB = fpA + ((size_t)N * 192 + 256);       // 2N*96 + 256
    _Float16* ypair = fpA;
    _Float16* hpair = fpB;
    _Float16* th    = fpA;

    // hist partials (12.8MB) alias fpA (19.2MB): dead after chunkpre.
    // cpre (64*N ints = 12.8MB) aliases fpB (19.2MB): dead after scatter8;
    // hpair written only later by spmm1 (same-stream ordering).
    unsigned short* parts = (unsigned short*)fpA;
    int* cpre = (int*)fpB;

    int RS = (N + NRANGE - 1) / NRANGE;                   // 6250
    int ecpc = ((E + NCHUNK - 1) / NCHUNK + 3) & ~3;      // %4==0 for int4 loads
    hist2_kernel<<<NRANGE * NCHUNK, 256, 2 * RS * (int)sizeof(int), stream>>>(
        src, dst, parts, E, RS, ecpc);
    degred_kernel<<<(N + 255) / 256, 256, 0, stream>>>(parts, perm, deg_in, iperm,
                                                       norm_out, norm_in, N, RS);

    scanA_kernel<<<nb, 256, 0, stream>>>(deg_in, pre, bsums, N);
    scanB_kernel<<<1, 256, 0, stream>>>(bsums, nb);
    rowfin_kernel<<<nb, 256, 0, stream>>>(pre, bsums, row_start, N, E);
    chunkpre_kernel<<<(N + 255) / 256, 256, 0, stream>>>(parts, row_start, cpre, N, RS);
    scatter8_kernel<<<NRANGE * NCHUNK, 256, RS * (int)sizeof(int), stream>>>(
        src, dst, norm_out, cpre, edge2, E, N, RS, ecpc);

    histblk_kernel<<<nb, 256, 0, stream>>>(deg_in, hb, N, nb);
    int n2 = 256 * nb;
    int nb2 = (n2 + 255) / 256;
    scanA_kernel<<<nb2, 256, 0, stream>>>(hb, hpre, bsums, n2);
    scanB_kernel<<<1, 256, 0, stream>>>(bsums, nb2);
    place2_kernel<<<nb, 256, 0, stream>>>(deg_in, hpre, bsums, order, N, nb);

    int wtot = 96 * KP1 + 96 * 96 + 96 + 1;
    weights_prep<<<(wtot + 255) / 256, 256, 0, stream>>>(W1, W2, Wm, bm, w1th, w1tl,
                                                         w2th, w2tl, wsum, bsum, F, KP1);

    // ypair = fp16(x @ W1) with pair-write epilogue (A fp32), BM=32
    gemm_mfma<<<(N + 31) / 32, 256, 0, stream>>>(x, w1th, w1tl, ypair, iperm,
                                                 N, F, KP1);

    int nsb = (N + 31) / 32;
    spmm1_dual<<<nsb, dim3(12, 32), 0, stream>>>(
        (const half8_t*)ypair, row_start, edge2, order, norm_out, norm_in,
        b1, a1, (half8_t*)hpair, N);

    // th = fp16(hpair @ W2): whole-B-in-LDS single-barrier kernel (K=96)
    gemm_small<<<(2 * N + 63) / 64, 256, 0, stream>>>(hpair, w2th, w2tl, th, 2 * N);

    spmm2_dual<<<nsb, dim3(12, 32), 0, stream>>>(
        (const half8_t*)th, row_start, edge2, order, norm_in, b2, a2,
        wsum, bsum, out, N);
}

// Round 13
// 389.917 us; speedup vs baseline: 1.0388x; 1.0388x over previous
//
#include <hip/hip_runtime.h>

#define H96 96

typedef __attribute__((ext_vector_type(8))) short bf16x8_t;
typedef __attribute__((ext_vector_type(4))) float f32x4_t;
typedef __attribute__((ext_vector_type(8))) _Float16 half8_t;

// ---------------- degrees: node-range-partitioned LDS histograms (r11, -45us) ----------------
// ZERO global atomics (device-scope atomics write through to HBM ~32B each).
#define NRANGE 8
#define NCHUNK 64

__global__ __launch_bounds__(256) void hist2_kernel(const int* __restrict__ src,
                                                    const int* __restrict__ dst,
                                                    unsigned short* __restrict__ parts,
                                                    int E, int RS, int ecpc) {
    extern __shared__ int h[];            // [2][RS] ints
    int r = blockIdx.x >> 6;              // node range
    int c = blockIdx.x & 63;              // edge chunk
    int lo = r * RS;
    for (int i = threadIdx.x; i < 2 * RS; i += 256) h[i] = 0;
    __syncthreads();
    int e0 = c * ecpc;
    int e1 = min(e0 + ecpc, E);
    for (int base = e0 + threadIdx.x * 4; base < e1; base += 1024) {
        int cnt = min(4, e1 - base);
        if (cnt == 4) {
            int4 sv = *(const int4*)(src + base);
            int4 dv = *(const int4*)(dst + base);
            int a;
            a = sv.x - lo; if ((unsigned)a < (unsigned)RS) atomicAdd(&h[a], 1);
            a = sv.y - lo; if ((unsigned)a < (unsigned)RS) atomicAdd(&h[a], 1);
            a = sv.z - lo; if ((unsigned)a < (unsigned)RS) atomicAdd(&h[a], 1);
            a = sv.w - lo; if ((unsigned)a < (unsigned)RS) atomicAdd(&h[a], 1);
            a = dv.x - lo; if ((unsigned)a < (unsigned)RS) atomicAdd(&h[RS + a], 1);
            a = dv.y - lo; if ((unsigned)a < (unsigned)RS) atomicAdd(&h[RS + a], 1);
            a = dv.z - lo; if ((unsigned)a < (unsigned)RS) atomicAdd(&h[RS + a], 1);
            a = dv.w - lo; if ((unsigned)a < (unsigned)RS) atomicAdd(&h[RS + a], 1);
        } else {
            for (int k = 0; k < cnt; k++) {
                int a = src[base + k] - lo;
                if ((unsigned)a < (unsigned)RS) atomicAdd(&h[a], 1);
                a = dst[base + k] - lo;
                if ((unsigned)a < (unsigned)RS) atomicAdd(&h[RS + a], 1);
            }
        }
    }
    __syncthreads();
    // parts layout: [range][p(src/dst)][chunk][RS] ushort
    unsigned short* po = parts + ((size_t)(r * 2 + 0) * NCHUNK + c) * RS;
    unsigned short* pi = parts + ((size_t)(r * 2 + 1) * NCHUNK + c) * RS;
    for (int i = threadIdx.x; i < RS; i += 256) {
        po[i] = (unsigned short)h[i];
        pi[i] = (unsigned short)h[RS + i];
    }
}

// reduce partials -> degrees, norms, iperm (fused)
__global__ void degred_kernel(const unsigned short* __restrict__ parts,
                              const int* __restrict__ perm,
                              int* __restrict__ deg_in, int* __restrict__ iperm,
                              float* __restrict__ no, float* __restrict__ ni,
                              int N, int RS) {
    int i = blockIdx.x * 256 + threadIdx.x;
    if (i >= N) return;
    int r = i / RS, idx = i - r * RS;
    const unsigned short* po = parts + ((size_t)(r * 2 + 0) * NCHUNK) * RS + idx;
    const unsigned short* pi = parts + ((size_t)(r * 2 + 1) * NCHUNK) * RS + idx;
    int so = 0, si = 0;
#pragma unroll
    for (int c = 0; c < NCHUNK; c++) {
        so += po[(size_t)c * RS];
        si += pi[(size_t)c * RS];
    }
    deg_in[i] = si;
    no[i] = rsqrtf(fmaxf((float)so, 1.0f));
    ni[i] = rsqrtf(fmaxf((float)si, 1.0f));
    iperm[perm[i]] = i;
}

// exact per-(chunk,node) CSR base positions from hist2 partials
__global__ void chunkpre_kernel(const unsigned short* __restrict__ parts,
                                const int* __restrict__ row_start,
                                int* __restrict__ cpre, int N, int RS) {
    int i = blockIdx.x * 256 + threadIdx.x;
    if (i >= N) return;
    int r = i / RS, idx = i - r * RS;
    const unsigned short* pi = parts + ((size_t)(r * 2 + 1) * NCHUNK) * RS + idx;
    int run = row_start[i];
#pragma unroll
    for (int c = 0; c < NCHUNK; c++) {
        cpre[(size_t)c * N + i] = run;
        run += pi[(size_t)c * RS];
    }
}

// ---------------- generic exclusive scan ----------------
__global__ void scanA_kernel(const int* __restrict__ in, int* __restrict__ pre,
                             int* __restrict__ bsums, int n) {
    __shared__ int s[256];
    int i = blockIdx.x * 256 + threadIdx.x;
    int v = (i < n) ? in[i] : 0;
    s[threadIdx.x] = v;
    __syncthreads();
    for (int off = 1; off < 256; off <<= 1) {
        int t = (threadIdx.x >= off) ? s[threadIdx.x - off] : 0;
        __syncthreads();
        s[threadIdx.x] += t;
        __syncthreads();
    }
    if (i < n) pre[i] = s[threadIdx.x] - v;
    if (threadIdx.x == 255) bsums[blockIdx.x] = s[255];
}

__global__ void scanB_kernel(int* __restrict__ bsums, int nb) {
    __shared__ int s[256];
    int v = (threadIdx.x < nb) ? bsums[threadIdx.x] : 0;
    s[threadIdx.x] = v;
    __syncthreads();
    for (int off = 1; off < 256; off <<= 1) {
        int t = (threadIdx.x >= off) ? s[threadIdx.x - off] : 0;
        __syncthreads();
        s[threadIdx.x] += t;
        __syncthreads();
    }
    if (threadIdx.x < nb) bsums[threadIdx.x] = s[threadIdx.x] - v;
}

__global__ void rowfin_kernel(const int* __restrict__ pre, const int* __restrict__ bsums,
                              int* __restrict__ row_start, int N, int E) {
    int i = blockIdx.x * 256 + threadIdx.x;
    if (i < N) row_start[i] = pre[i] + bsums[blockIdx.x];
    if (i == 0) row_start[N] = E;
}

// CSR scatter: range x chunk blocks, LDS cursors seeded from cpre. No global atomics.
__global__ __launch_bounds__(256) void scatter8_kernel(const int* __restrict__ src,
                                                       const int* __restrict__ dst,
                                                       const float* __restrict__ norm_out,
                                                       const int* __restrict__ cpre,
                                                       int2* __restrict__ edge2,
                                                       int E, int N, int RS, int ecpc) {
    extern __shared__ int cur[];          // RS ints
    int r = blockIdx.x >> 6, c = blockIdx.x & 63;
    int lo = r * RS;
    int len = min(RS, N - lo);
    for (int i = threadIdx.x; i < len; i += 256)
        cur[i] = cpre[(size_t)c * N + lo + i];
    __syncthreads();
    int e0 = c * ecpc, e1 = min(e0 + ecpc, E);
    for (int e = e0 + threadIdx.x; e < e1; e += 256) {
        int d = dst[e] - lo;
        if ((unsigned)d < (unsigned)len) {
            int s = src[e];
            int p = atomicAdd(&cur[d], 1);
            edge2[p] = make_int2(s, __float_as_int(norm_out[s]));
        }
    }
}

// ---------------- low-contention counting sort by deg_in ----------------
__global__ void histblk_kernel(const int* __restrict__ deg, int* __restrict__ hb,
                               int N, int nb) {
    __shared__ int h[256];
    h[threadIdx.x] = 0;
    __syncthreads();
    int i = blockIdx.x * 256 + threadIdx.x;
    if (i < N) atomicAdd(&h[min(deg[i], 255)], 1);
    __syncthreads();
    hb[threadIdx.x * nb + blockIdx.x] = h[threadIdx.x];
}

__global__ void place2_kernel(const int* __restrict__ deg, const int* __restrict__ hpre,
                              const int* __restrict__ bsums, int* __restrict__ order,
                              int N, int nb) {
    __shared__ int cur[256];
    int idx = threadIdx.x * nb + blockIdx.x;
    cur[threadIdx.x] = hpre[idx] + bsums[idx >> 8];
    __syncthreads();
    int i = blockIdx.x * 256 + threadIdx.x;
    if (i < N) {
        int b = min(deg[i], 255);
        int p = atomicAdd(&cur[b], 1);
        order[p] = i;
    }
}

// ---------------- bf16 hi/lo split helpers ----------------
__device__ __forceinline__ void f2bf2(float v, unsigned short& h, unsigned short& l) {
    unsigned int b = __float_as_uint(v);
    unsigned short hh = (unsigned short)((b + 0x7FFFu + ((b >> 16) & 1u)) >> 16);
    float fh = __uint_as_float(((unsigned int)hh) << 16);
    float r = v - fh;
    unsigned int rb = __float_as_uint(r);
    unsigned short ll = (unsigned short)((rb + 0x7FFFu + ((rb >> 16) & 1u)) >> 16);
    h = hh; l = ll;
}

__device__ __forceinline__ void cvt8(const float f[8], bf16x8_t& ah, bf16x8_t& al) {
    union { unsigned int u[4]; bf16x8_t v; } H, L;
#pragma unroll
    for (int i = 0; i < 4; i++) {
        float v0 = f[2 * i], v1 = f[2 * i + 1];
        unsigned int b0 = __float_as_uint(v0);
        unsigned int b1 = __float_as_uint(v1);
        unsigned int m0 = b0 & 0xFFFF0000u;
        unsigned int m1 = b1 & 0xFFFF0000u;
        float r0 = v0 - __uint_as_float(m0);
        float r1 = v1 - __uint_as_float(m1);
        H.u[i] = (b0 >> 16) | m1;
        L.u[i] = (__float_as_uint(r0) >> 16) | (__float_as_uint(r1) & 0xFFFF0000u);
    }
    ah = H.v; al = L.v;
}

// fused weights prep
__global__ void weights_prep(const float* __restrict__ W1, const float* __restrict__ W2,
                             const float* __restrict__ Wm, const float* __restrict__ bm,
                             unsigned short* __restrict__ w1h, unsigned short* __restrict__ w1l,
                             unsigned short* __restrict__ w2h, unsigned short* __restrict__ w2l,
                             float* __restrict__ wsum, float* __restrict__ bsum,
                             int F, int KP1) {
    int idx = blockIdx.x * 256 + threadIdx.x;
    int z1 = 96 * KP1, z2 = z1 + 96 * 96;
    if (idx < z1) {
        int n = idx / KP1, k = idx - n * KP1;
        float v = (k < F) ? W1[(size_t)k * 96 + n] : 0.f;
        unsigned short h, l;
        f2bf2(v, h, l);
        w1h[idx] = h; w1l[idx] = l;
    } else if (idx < z2) {
        int t = idx - z1;
        int n = t / 96, k = t - n * 96;
        float v = W2[(size_t)k * 96 + n];
        unsigned short h, l;
        f2bf2(v, h, l);
        w2h[t] = h; w2l[t] = l;
    } else if (idx < z2 + 96) {
        int c = idx - z2;
        float s = 0.f;
        for (int j = 0; j < 96; j++) s += Wm[c * 96 + j];
        wsum[c] = s;
    } else if (idx == z2 + 96) {
        float s = 0.f;
        for (int j = 0; j < 96; j++) s += bm[j];
        bsum[0] = s;
    }
}

#define GBK 32

__device__ __forceinline__ void gload_lds16(const void* g, void* l) {
    __builtin_amdgcn_global_load_lds(
        (const __attribute__((address_space(1))) unsigned int*)g,
        (__attribute__((address_space(3))) unsigned int*)l, 16, 0, 0);
}

// ---------------- async-LDS-B bf16x3 MFMA GEMM, BM=64, depth-2 A prefetch (r13) ----------------
// r13 vs r11 (r12's BM=32 reverted: staging amortization loss, 87us):
// ONLY change from the thrice-passed r11 skeleton: A-prefetch depth 2.
// Body: stage(t+1) -> vmcnt(5)+barrier -> cvt8(A(t)) -> loadA(t+2) into the
// freed registers -> MFMAs -> lgkm+barrier. Ledger at the wait (steady):
// outstanding = A(t)[2],stage(t)[3],A(t+1)[2],stage(t+1)[3] = 10; oldest 5 =
// exactly {A(t),stage(t)} -> vmcnt(5) (same value as r11). A's HBM latency
// (~900cy) now spans ~2 barrier rounds instead of 1.
__global__ __launch_bounds__(256, 6) void gemm_mfma(const void* __restrict__ Av,
                                                    const unsigned short* __restrict__ Bth,
                                                    const unsigned short* __restrict__ Btl,
                                                    _Float16* __restrict__ C16,
                                                    const int* __restrict__ ipermArr,
                                                    int M, int K, int KP) {
    // [buf][part][row][slot][8 halfs] = 2*2*96*4*8 ush = 24576 B
    __shared__ alignas(16) unsigned short Bs[2][2][96][4][8];
    int tid = threadIdx.x;
    int wid = tid >> 6, lane = tid & 63;
    int q = lane >> 4, mn = lane & 15;
    int row0 = blockIdx.x * 64 + wid * 16;
    int arow = min(row0 + mn, M - 1);   // clamp (no predication): uniform VMEM count
    int nk = (K + GBK - 1) / GBK;

    const float* A32 = (const float*)Av;

    const unsigned short* gsrc[3];
    int lbase[3];
#pragma unroll
    for (int i = 0; i < 3; i++) {
        int c = wid * 192 + i * 64 + lane;
        int part = (c >= 384) ? 1 : 0;
        int rem = c - part * 384;
        int row = rem >> 2, slot = rem & 3;
        int kc = slot ^ ((row >> 1) & 3);
        gsrc[i] = (part ? Btl : Bth) + (size_t)row * KP + kc * 8;
        lbase[i] = (wid * 192 + i * 64) * 8;   // wave-uniform chunk-linear dest
    }

    auto stage = [&](int t, int buf) {
#pragma unroll
        for (int i = 0; i < 3; i++)
            gload_lds16(gsrc[i] + (size_t)t * GBK, &Bs[buf][0][0][0][0] + lbase[i]);
    };

    auto loadA = [&](int t, float* f) {
        int gk = t * GBK + q * 8;
        if (gk + 8 <= K) {
            float4 v0 = *(const float4*)(A32 + (size_t)arow * K + gk);
            float4 v1 = *(const float4*)(A32 + (size_t)arow * K + gk + 4);
            f[0] = v0.x; f[1] = v0.y; f[2] = v0.z; f[3] = v0.w;
            f[4] = v1.x; f[5] = v1.y; f[6] = v1.z; f[7] = v1.w;
        } else {
#pragma unroll
            for (int c = 0; c < 8; c++)
                f[c] = (gk + c < K) ? A32[(size_t)arow * K + gk + c] : 0.f;
        }
    };

    f32x4_t acc[6] = {};
    int slotR = q ^ ((mn >> 1) & 3);

    auto body = [&](int t, float (&cur)[8]) {
        int tn1 = (t + 1 < nk) ? t + 1 : nk - 1;   // clamped: uniform issue count
        stage(tn1, (t + 1) & 1);
        asm volatile("s_waitcnt vmcnt(5)" ::: "memory");
        __builtin_amdgcn_sched_barrier(0);
        __builtin_amdgcn_s_barrier();

        bf16x8_t ah, al;
        cvt8(cur, ah, al);                         // consume A(t)
        int tn2 = (t + 2 < nk) ? t + 2 : nk - 1;
        loadA(tn2, cur);                           // A(t+2) into freed regs

        const unsigned short* bp = &Bs[t & 1][0][0][0][0] + mn * 32 + slotR * 8;
#pragma unroll
        for (int ct = 0; ct < 6; ct++) {
            bf16x8_t bh = *(const bf16x8_t*)(bp + ct * 512);
            bf16x8_t bl = *(const bf16x8_t*)(bp + 3072 + ct * 512);
            acc[ct] = __builtin_amdgcn_mfma_f32_16x16x32_bf16(ah, bh, acc[ct], 0, 0, 0);
            acc[ct] = __builtin_amdgcn_mfma_f32_16x16x32_bf16(ah, bl, acc[ct], 0, 0, 0);
            acc[ct] = __builtin_amdgcn_mfma_f32_16x16x32_bf16(al, bh, acc[ct], 0, 0, 0);
        }
        // all reads of buf[t&1] done before anyone stages into it next iter
        asm volatile("s_waitcnt lgkmcnt(0)" ::: "memory");
        __builtin_amdgcn_sched_barrier(0);
        __builtin_amdgcn_s_barrier();
    };

    float f0[8], f1[8];
    stage(0, 0);
    loadA(0, f0);
    loadA(1, f1);

    for (int t0 = 0; t0 < nk; t0 += 2) {
        body(t0, f0);
        if (t0 + 1 < nk) body(t0 + 1, f1);   // uniform cond (nk block-uniform)
    }

    // drain outstanding VMEM (incl. LDS-destined staging loads) before exit
    asm volatile("s_waitcnt vmcnt(0)" ::: "memory");
    __builtin_amdgcn_sched_barrier(0);

#pragma unroll
    for (int reg = 0; reg < 4; reg++) {
        int gr = row0 + q * 4 + reg;
        if (gr < M) {
            int ip = ipermArr[gr];
#pragma unroll
            for (int ct = 0; ct < 6; ct++) {
                _Float16 v = (_Float16)acc[ct][reg];
                C16[(size_t)gr * 192 + ct * 16 + mn] = v;        // ypair[gr][0]
                C16[(size_t)ip * 192 + 96 + ct * 16 + mn] = v;   // ypair[iperm[gr]][1]
            }
        }
    }
}

// ---------------- gemm_small: K=96 whole-B-in-LDS, single-barrier (r10, passed) ----------------
__global__ __launch_bounds__(256, 4) void gemm_small(const _Float16* __restrict__ A16,
                                                     const unsigned short* __restrict__ Bth,
                                                     const unsigned short* __restrict__ Btl,
                                                     _Float16* __restrict__ C16,
                                                     int M) {
    __shared__ alignas(16) unsigned short Bs[3][2][96][4][8];   // 36864 B
    const int K = 96;
    int tid = threadIdx.x;
    int wid = tid >> 6, lane = tid & 63;
    int q = lane >> 4, mn = lane & 15;
    int row0 = blockIdx.x * 64 + wid * 16;
    int arow = min(row0 + mn, M - 1);

    const unsigned short* gsrc[3];
    int lbase[3];
#pragma unroll
    for (int i = 0; i < 3; i++) {
        int c = wid * 192 + i * 64 + lane;
        int part = (c >= 384) ? 1 : 0;
        int rem = c - part * 384;
        int row = rem >> 2, slot = rem & 3;
        int kc = slot ^ ((row >> 1) & 3);
        gsrc[i] = (part ? Btl : Bth) + (size_t)row * K + kc * 8;
        lbase[i] = (wid * 192 + i * 64) * 8;
    }

#pragma unroll
    for (int t = 0; t < 3; t++)
#pragma unroll
        for (int i = 0; i < 3; i++)
            gload_lds16(gsrc[i] + (size_t)t * GBK, &Bs[t][0][0][0][0] + lbase[i]);

    uint4 ra0 = *(const uint4*)(A16 + (size_t)arow * K + 0 * GBK + q * 8);
    uint4 ra1 = *(const uint4*)(A16 + (size_t)arow * K + 1 * GBK + q * 8);
    uint4 ra2 = *(const uint4*)(A16 + (size_t)arow * K + 2 * GBK + q * 8);

    asm volatile("s_waitcnt vmcnt(0)" ::: "memory");
    __builtin_amdgcn_sched_barrier(0);
    __builtin_amdgcn_s_barrier();

    f32x4_t acc[6] = {};
    int slotR = q ^ ((mn >> 1) & 3);

    auto step = [&](int t, const uint4& raw) {
        float f[8];
        const _Float16* hp = (const _Float16*)&raw;
#pragma unroll
        for (int c = 0; c < 8; c++) f[c] = (float)hp[c];
        bf16x8_t ah, al;
        cvt8(f, ah, al);
        const unsigned short* bp = &Bs[t][0][0][0][0] + mn * 32 + slotR * 8;
#pragma unroll
        for (int ct = 0; ct < 6; ct++) {
            bf16x8_t bh = *(const bf16x8_t*)(bp + ct * 512);
            bf16x8_t bl = *(const bf16x8_t*)(bp + 3072 + ct * 512);
            acc[ct] = __builtin_amdgcn_mfma_f32_16x16x32_bf16(ah, bh, acc[ct], 0, 0, 0);
            acc[ct] = __builtin_amdgcn_mfma_f32_16x16x32_bf16(ah, bl, acc[ct], 0, 0, 0);
            acc[ct] = __builtin_amdgcn_mfma_f32_16x16x32_bf16(al, bh, acc[ct], 0, 0, 0);
        }
    };

    step(0, ra0);
    step(1, ra1);
    step(2, ra2);

#pragma unroll
    for (int reg = 0; reg < 4; reg++) {
        int gr = row0 + q * 4 + reg;
        if (gr < M) {
#pragma unroll
            for (int ct = 0; ct < 6; ct++)
                C16[(size_t)gr * H96 + ct * 16 + mn] = (_Float16)acc[ct][reg];
        }
    }
}

// ---------------- helpers ----------------
__device__ __forceinline__ void fmah8(float4& a, float4& b, float s, half8_t v) {
    a.x = fmaf(s, (float)v[0], a.x); a.y = fmaf(s, (float)v[1], a.y);
    a.z = fmaf(s, (float)v[2], a.z); a.w = fmaf(s, (float)v[3], a.w);
    b.x = fmaf(s, (float)v[4], b.x); b.y = fmaf(s, (float)v[5], b.y);
    b.z = fmaf(s, (float)v[6], b.z); b.w = fmaf(s, (float)v[7], b.w);
}

__device__ __forceinline__ float4 prelu4(float4 acc, float ni, float4 b, float4 a) {
    float4 h;
    h.x = fmaf(acc.x, ni, b.x); h.x = (h.x >= 0.f) ? h.x : a.x * h.x;
    h.y = fmaf(acc.y, ni, b.y); h.y = (h.y >= 0.f) ? h.y : a.y * h.y;
    h.z = fmaf(acc.z, ni, b.z); h.z = (h.z >= 0.f) ? h.z : a.z * h.z;
    h.w = fmaf(acc.w, ni, b.w); h.w = (h.w >= 0.f) ? h.w : a.w * h.w;
    return h;
}

// ---------------- layer-1 dual-view SpMM over PAIRED fp16 table ----------------
__global__ __launch_bounds__(384) void spmm1_dual(
        const half8_t* __restrict__ yp, const int* __restrict__ row_start,
        const int2* __restrict__ edge2, const int* __restrict__ order,
        const float* __restrict__ norm_out, const float* __restrict__ norm_in,
        const float* __restrict__ b1, const float* __restrict__ a1,
        half8_t* __restrict__ hpair, int N) {
    int g = blockIdx.x * 32 + threadIdx.y;
    if (g >= N) return;
    int d = order[g];
    int tx = threadIdx.x;
    int beg = row_start[d], end = row_start[d + 1];
    const half8_t* yt = yp + tx;
    float4 a1a = {0,0,0,0}, a1b = {0,0,0,0}, a2a = {0,0,0,0}, a2b = {0,0,0,0};
    int j = beg;
    for (; j + 8 <= end; j += 8) {
        int2 e[8];
#pragma unroll
        for (int q = 0; q < 8; q++) e[q] = edge2[j + q];
        half8_t u[8], w[8];
#pragma unroll
        for (int q = 0; q < 8; q++) u[q] = yt[(size_t)e[q].x * 24];
#pragma unroll
        for (int q = 0; q < 8; q++) w[q] = yt[(size_t)e[q].x * 24 + 12];
#pragma unroll
        for (int q = 0; q < 8; q++) {
            float n = __int_as_float(e[q].y);
            fmah8(a1a, a1b, n, u[q]);
            fmah8(a2a, a2b, n, w[q]);
        }
    }
    for (; j < end; j++) {
        int2 e = edge2[j];
        float n = __int_as_float(e.y);
        fmah8(a1a, a1b, n, yt[(size_t)e.x * 24]);
        fmah8(a2a, a2b, n, yt[(size_t)e.x * 24 + 12]);
    }
    float ni = norm_in[d], no = norm_out[d];
    float4 bb0 = ((const float4*)b1)[tx * 2], bb1 = ((const float4*)b1)[tx * 2 + 1];
    float4 aa0 = ((const float4*)a1)[tx * 2], aa1 = ((const float4*)a1)[tx * 2 + 1];
    float4 r1a = prelu4(a1a, ni, bb0, aa0), r1b = prelu4(a1b, ni, bb1, aa1);
    float4 r2a = prelu4(a2a, ni, bb0, aa0), r2b = prelu4(a2b, ni, bb1, aa1);
    half8_t o1, o2;
    o1[0] = (_Float16)(r1a.x * no); o1[1] = (_Float16)(r1a.y * no);
    o1[2] = (_Float16)(r1a.z * no); o1[3] = (_Float16)(r1a.w * no);
    o1[4] = (_Float16)(r1b.x * no); o1[5] = (_Float16)(r1b.y * no);
    o1[6] = (_Float16)(r1b.z * no); o1[7] = (_Float16)(r1b.w * no);
    o2[0] = (_Float16)(r2a.x * no); o2[1] = (_Float16)(r2a.y * no);
    o2[2] = (_Float16)(r2a.z * no); o2[3] = (_Float16)(r2a.w * no);
    o2[4] = (_Float16)(r2b.x * no); o2[5] = (_Float16)(r2b.y * no);
    o2[6] = (_Float16)(r2b.z * no); o2[7] = (_Float16)(r2b.w * no);
    hpair[(size_t)d * 24 + tx] = o1;
    hpair[(size_t)d * 24 + 12 + tx] = o2;
}

// ---------------- layer-2 dual-view SpMM over node-interleaved t table ----------------
__global__ __launch_bounds__(384) void spmm2_dual(
        const half8_t* __restrict__ th,
        const int* __restrict__ row_start, const int2* __restrict__ edge2,
        const int* __restrict__ order, const float* __restrict__ norm_in,
        const float* __restrict__ b2, const float* __restrict__ a2,
        const float* __restrict__ wsum, const float* __restrict__ bsum,
        float* __restrict__ outp, int N) {
    int g = blockIdx.x * 32 + threadIdx.y;
    int tx = threadIdx.x;
    int ty = threadIdx.y;
    bool valid = (g < N);
    int d = valid ? order[g] : 0;
    int beg = 0, end = 0;
    if (valid) { beg = row_start[d]; end = row_start[d + 1]; }
    const half8_t* t1 = th + tx;
    float4 a1a = {0,0,0,0}, a1b = {0,0,0,0}, a2a = {0,0,0,0}, a2b = {0,0,0,0};
    int j = beg;
    for (; j + 8 <= end; j += 8) {
        int s[8];
#pragma unroll
        for (int q = 0; q < 8; q++) s[q] = edge2[j + q].x;
        half8_t u[8], w[8];
#pragma unroll
        for (int q = 0; q < 8; q++) u[q] = t1[(size_t)s[q] * 24];
#pragma unroll
        for (int q = 0; q < 8; q++) w[q] = t1[(size_t)s[q] * 24 + 12];
#pragma unroll
        for (int q = 0; q < 8; q++) {
            fmah8(a1a, a1b, 1.f, u[q]);
            fmah8(a2a, a2b, 1.f, w[q]);
        }
    }
    for (; j < end; j++) {
        int s = edge2[j].x;
        fmah8(a1a, a1b, 1.f, t1[(size_t)s * 24]);
        fmah8(a2a, a2b, 1.f, t1[(size_t)s * 24 + 12]);
    }
    float ni = valid ? norm_in[d] : 0.f;
    float4 bb0 = ((const float4*)b2)[tx * 2], bb1 = ((const float4*)b2)[tx * 2 + 1];
    float4 aa0 = ((const float4*)a2)[tx * 2], aa1 = ((const float4*)a2)[tx * 2 + 1];
    float4 wv0 = ((const float4*)wsum)[tx * 2], wv1 = ((const float4*)wsum)[tx * 2 + 1];
    float4 r1a = prelu4(a1a, ni, bb0, aa0), r1b = prelu4(a1b, ni, bb1, aa1);
    float4 r2a = prelu4(a2a, ni, bb0, aa0), r2b = prelu4(a2b, ni, bb1, aa1);
    float p1 = r1a.x * wv0.x + r1a.y * wv0.y + r1a.z * wv0.z + r1a.w * wv0.w
             + r1b.x * wv1.x + r1b.y * wv1.y + r1b.z * wv1.z + r1b.w * wv1.w;
    float p2 = r2a.x * wv0.x + r2a.y * wv0.y + r2a.z * wv0.z + r2a.w * wv0.w
             + r2b.x * wv1.x + r2b.y * wv1.y + r2b.z * wv1.z + r2b.w * wv1.w;
    __shared__ float red1[32][12];
    __shared__ float red2[32][12];
    red1[ty][tx] = p1;
    red2[ty][tx] = p2;
    __syncthreads();
    if (tx == 0 && valid) {
        float s1 = 0.f, s2 = 0.f;
#pragma unroll
        for (int k = 0; k < 12; k++) { s1 += red1[ty][k]; s2 += red2[ty][k]; }
        outp[d] = s1 + bsum[0];
        outp[N + d] = s2 + bsum[0];
    }
}

extern "C" void kernel_launch(void* const* d_in, const int* in_sizes, int n_in,
                              void* d_out, int out_size, void* d_ws, size_t ws_size,
                              hipStream_t stream) {
    const float* x    = (const float*)d_in[0];
    const int*   src  = (const int*)d_in[1];
    const int*   dst  = (const int*)d_in[2];
    const int*   perm = (const int*)d_in[3];
    const float* W1   = (const float*)d_in[4];
    const float* b1   = (const float*)d_in[5];
    const float* a1   = (const float*)d_in[6];
    const float* W2   = (const float*)d_in[7];
    const float* b2   = (const float*)d_in[8];
    const float* a2   = (const float*)d_in[9];
    const float* Wm   = (const float*)d_in[10];
    const float* bm   = (const float*)d_in[11];
    float* out = (float*)d_out;

    int E = in_sizes[1];
    int N = in_sizes[3];
    int F = in_sizes[0] / N;               // 500
    int KP1 = ((F + GBK - 1) / GBK) * GBK; // 512

    size_t NP = ((size_t)N + 256) & ~(size_t)255;
    size_t EP = ((size_t)E + 255) & ~(size_t)255;
    int nb = (N + 255) / 256;
    size_t HB = ((size_t)256 * nb + 255) & ~(size_t)255;

    int* iperm     = (int*)d_ws;          // NP
    int* deg_in    = iperm + NP;          // NP
    int* pre       = deg_in + NP;         // NP
    int* row_start = pre + NP;            // NP
    int* cursor    = row_start + NP;      // NP (unused slot, kept for layout)
    int* order     = cursor + NP;         // NP
    int* bsums     = order + NP;          // 256
    int* hb        = bsums + 256;         // HB
    int* hpre      = hb + HB;             // HB
    int2* edge2    = (int2*)(hpre + HB);  // EP int2 (6.4MB)
    float* norm_out = (float*)(edge2 + EP);    // NP
    float* norm_in  = norm_out + NP;           // NP
    float* wsum     = norm_in + NP;            // 128
    float* bsum     = wsum + 128;              // 128
    unsigned short* w1th = (unsigned short*)(bsum + 128); // 96*KP1 pad 49664
    unsigned short* w1tl = w1th + 49664;
    unsigned short* w2th = w1tl + 49664;                  // 96*96 pad 9728
    unsigned short* w2tl = w2th + 9728;
    // fp16 scratch: fpA = ypair then th (aliased; ypair dead after spmm1),
    // fpB = hpair.
    _Float16* fpA = (_Float16*)(w2tl + 9728);            // N*192 + 256
    _Float16* fpB = fpA + ((size_t)N * 192 + 256);       // 2N*96 + 256
    _Float16* ypair = fpA;
    _Float16* hpair = fpB;
    _Float16* th    = fpA;

    // hist partials (12.8MB) alias fpA (19.2MB): dead after chunkpre.
    // cpre (64*N ints = 12.8MB) aliases fpB (19.2MB): dead after scatter8;
    // hpair written only later by spmm1 (same-stream ordering).
    unsigned short* parts = (unsigned short*)fpA;
    int* cpre = (int*)fpB;

    int RS = (N + NRANGE - 1) / NRANGE;                   // 6250
    int ecpc = ((E + NCHUNK - 1) / NCHUNK + 3) & ~3;      // %4==0 for int4 loads
    hist2_kernel<<<NRANGE * NCHUNK, 256, 2 * RS * (int)sizeof(int), stream>>>(
        src, dst, parts, E, RS, ecpc);
    degred_kernel<<<(N + 255) / 256, 256, 0, stream>>>(parts, perm, deg_in, iperm,
                                                       norm_out, norm_in, N, RS);

    scanA_kernel<<<nb, 256, 0, stream>>>(deg_in, pre, bsums, N);
    scanB_kernel<<<1, 256, 0, stream>>>(bsums, nb);
    rowfin_kernel<<<nb, 256, 0, stream>>>(pre, bsums, row_start, N, E);
    chunkpre_kernel<<<(N + 255) / 256, 256, 0, stream>>>(parts, row_start, cpre, N, RS);
    scatter8_kernel<<<NRANGE * NCHUNK, 256, RS * (int)sizeof(int), stream>>>(
        src, dst, norm_out, cpre, edge2, E, N, RS, ecpc);

    histblk_kernel<<<nb, 256, 0, stream>>>(deg_in, hb, N, nb);
    int n2 = 256 * nb;
    int nb2 = (n2 + 255) / 256;
    scanA_kernel<<<nb2, 256, 0, stream>>>(hb, hpre, bsums, n2);
    scanB_kernel<<<1, 256, 0, stream>>>(bsums, nb2);
    place2_kernel<<<nb, 256, 0, stream>>>(deg_in, hpre, bsums, order, N, nb);

    int wtot = 96 * KP1 + 96 * 96 + 96 + 1;
    weights_prep<<<(wtot + 255) / 256, 256, 0, stream>>>(W1, W2, Wm, bm, w1th, w1tl,
                                                         w2th, w2tl, wsum, bsum, F, KP1);

    // ypair = fp16(x @ W1) with pair-write epilogue (A fp32), BM=64 depth-2-A
    gemm_mfma<<<(N + 63) / 64, 256, 0, stream>>>(x, w1th, w1tl, ypair, iperm,
                                                 N, F, KP1);

    int nsb = (N + 31) / 32;
    spmm1_dual<<<nsb, dim3(12, 32), 0, stream>>>(
        (const half8_t*)ypair, row_start, edge2, order, norm_out, norm_in,
        b1, a1, (half8_t*)hpair, N);

    // th = fp16(hpair @ W2): whole-B-in-LDS single-barrier kernel (K=96)
    gemm_small<<<(2 * N + 63) / 64, 256, 0, stream>>>(hpair, w2th, w2tl, th, 2 * N);

    spmm2_dual<<<nsb, dim3(12, 32), 0, stream>>>(
        (const half8_t*)th, row_start, edge2, order, norm_in, b2, a2,
        wsum, bsum, out, N);
}

// Round 15
// 377.135 us; speedup vs baseline: 1.0740x; 1.0339x over previous
//
#include <hip/hip_runtime.h>

#define H96 96

typedef __attribute__((ext_vector_type(8))) short bf16x8_t;
typedef __attribute__((ext_vector_type(4))) float f32x4_t;
typedef __attribute__((ext_vector_type(8))) _Float16 half8_t;

// ---------------- degrees: node-range-partitioned LDS histograms (r11, -45us) ----------------
// ZERO global atomics (device-scope atomics write through to HBM ~32B each).
// r15: weights_prep grid-folded into this launch (blocks >= NRANGE*NCHUNK).
#define NRANGE 8
#define NCHUNK 64

__device__ __forceinline__ void f2bf2(float v, unsigned short& h, unsigned short& l) {
    unsigned int b = __float_as_uint(v);
    unsigned short hh = (unsigned short)((b + 0x7FFFu + ((b >> 16) & 1u)) >> 16);
    float fh = __uint_as_float(((unsigned int)hh) << 16);
    float r = v - fh;
    unsigned int rb = __float_as_uint(r);
    unsigned short ll = (unsigned short)((rb + 0x7FFFu + ((rb >> 16) & 1u)) >> 16);
    h = hh; l = ll;
}

__global__ __launch_bounds__(256) void hist2w_kernel(
        const int* __restrict__ src, const int* __restrict__ dst,
        unsigned short* __restrict__ parts, int E, int RS, int ecpc,
        const float* __restrict__ W1, const float* __restrict__ W2,
        const float* __restrict__ Wm, const float* __restrict__ bm,
        unsigned short* __restrict__ w1h, unsigned short* __restrict__ w1l,
        unsigned short* __restrict__ w2h, unsigned short* __restrict__ w2l,
        float* __restrict__ wsum, float* __restrict__ bsum, int F, int KP1) {
    if (blockIdx.x >= NRANGE * NCHUNK) {
        // ---- weights_prep path (grid-folded; ignores LDS) ----
        int idx = (blockIdx.x - NRANGE * NCHUNK) * 256 + threadIdx.x;
        int z1 = 96 * KP1, z2 = z1 + 96 * 96;
        if (idx < z1) {
            int n = idx / KP1, k = idx - n * KP1;
            float v = (k < F) ? W1[(size_t)k * 96 + n] : 0.f;
            unsigned short h, l;
            f2bf2(v, h, l);
            w1h[idx] = h; w1l[idx] = l;
        } else if (idx < z2) {
            int t = idx - z1;
            int n = t / 96, k = t - n * 96;
            float v = W2[(size_t)k * 96 + n];
            unsigned short h, l;
            f2bf2(v, h, l);
            w2h[t] = h; w2l[t] = l;
        } else if (idx < z2 + 96) {
            int c = idx - z2;
            float s = 0.f;
            for (int j = 0; j < 96; j++) s += Wm[c * 96 + j];
            wsum[c] = s;
        } else if (idx == z2 + 96) {
            float s = 0.f;
            for (int j = 0; j < 96; j++) s += bm[j];
            bsum[0] = s;
        }
        return;
    }
    extern __shared__ int h[];            // [2][RS] ints
    int r = blockIdx.x >> 6;              // node range
    int c = blockIdx.x & 63;              // edge chunk
    int lo = r * RS;
    for (int i = threadIdx.x; i < 2 * RS; i += 256) h[i] = 0;
    __syncthreads();
    int e0 = c * ecpc;
    int e1 = min(e0 + ecpc, E);
    for (int base = e0 + threadIdx.x * 4; base < e1; base += 1024) {
        int cnt = min(4, e1 - base);
        if (cnt == 4) {
            int4 sv = *(const int4*)(src + base);
            int4 dv = *(const int4*)(dst + base);
            int a;
            a = sv.x - lo; if ((unsigned)a < (unsigned)RS) atomicAdd(&h[a], 1);
            a = sv.y - lo; if ((unsigned)a < (unsigned)RS) atomicAdd(&h[a], 1);
            a = sv.z - lo; if ((unsigned)a < (unsigned)RS) atomicAdd(&h[a], 1);
            a = sv.w - lo; if ((unsigned)a < (unsigned)RS) atomicAdd(&h[a], 1);
            a = dv.x - lo; if ((unsigned)a < (unsigned)RS) atomicAdd(&h[RS + a], 1);
            a = dv.y - lo; if ((unsigned)a < (unsigned)RS) atomicAdd(&h[RS + a], 1);
            a = dv.z - lo; if ((unsigned)a < (unsigned)RS) atomicAdd(&h[RS + a], 1);
            a = dv.w - lo; if ((unsigned)a < (unsigned)RS) atomicAdd(&h[RS + a], 1);
        } else {
            for (int k = 0; k < cnt; k++) {
                int a = src[base + k] - lo;
                if ((unsigned)a < (unsigned)RS) atomicAdd(&h[a], 1);
                a = dst[base + k] - lo;
                if ((unsigned)a < (unsigned)RS) atomicAdd(&h[RS + a], 1);
            }
        }
    }
    __syncthreads();
    // parts layout: [range][p(src/dst)][chunk][RS] ushort
    unsigned short* po = parts + ((size_t)(r * 2 + 0) * NCHUNK + c) * RS;
    unsigned short* pi = parts + ((size_t)(r * 2 + 1) * NCHUNK + c) * RS;
    for (int i = threadIdx.x; i < RS; i += 256) {
        po[i] = (unsigned short)h[i];
        pi[i] = (unsigned short)h[RS + i];
    }
}

// reduce partials -> degrees, norms, iperm (fused)
__global__ void degred_kernel(const unsigned short* __restrict__ parts,
                              const int* __restrict__ perm,
                              int* __restrict__ deg_in, int* __restrict__ iperm,
                              float* __restrict__ no, float* __restrict__ ni,
                              int N, int RS) {
    int i = blockIdx.x * 256 + threadIdx.x;
    if (i >= N) return;
    int r = i / RS, idx = i - r * RS;
    const unsigned short* po = parts + ((size_t)(r * 2 + 0) * NCHUNK) * RS + idx;
    const unsigned short* pi = parts + ((size_t)(r * 2 + 1) * NCHUNK) * RS + idx;
    int so = 0, si = 0;
#pragma unroll
    for (int c = 0; c < NCHUNK; c++) {
        so += po[(size_t)c * RS];
        si += pi[(size_t)c * RS];
    }
    deg_in[i] = si;
    no[i] = rsqrtf(fmaxf((float)so, 1.0f));
    ni[i] = rsqrtf(fmaxf((float)si, 1.0f));
    iperm[perm[i]] = i;
}

// ---------------- generic exclusive scan (phase A) ----------------
__global__ void scanA_kernel(const int* __restrict__ in, int* __restrict__ pre,
                             int* __restrict__ bsums, int n) {
    __shared__ int s[256];
    int i = blockIdx.x * 256 + threadIdx.x;
    int v = (i < n) ? in[i] : 0;
    s[threadIdx.x] = v;
    __syncthreads();
    for (int off = 1; off < 256; off <<= 1) {
        int t = (threadIdx.x >= off) ? s[threadIdx.x - off] : 0;
        __syncthreads();
        s[threadIdx.x] += t;
        __syncthreads();
    }
    if (i < n) pre[i] = s[threadIdx.x] - v;
    if (threadIdx.x == 255) bsums[blockIdx.x] = s[255];
}

// r15 fused: scanB (in-LDS over raw bsums) + rowfin + chunkpre in ONE kernel.
__global__ void rowfinC_kernel(const int* __restrict__ pre, const int* __restrict__ bsums,
                               const unsigned short* __restrict__ parts,
                               int* __restrict__ row_start, int* __restrict__ cpre,
                               int N, int E, int RS, int nb) {
    __shared__ int sb[256];
    int v = (threadIdx.x < nb) ? bsums[threadIdx.x] : 0;
    sb[threadIdx.x] = v;
    __syncthreads();
    for (int off = 1; off < 256; off <<= 1) {
        int t = (threadIdx.x >= off) ? sb[threadIdx.x - off] : 0;
        __syncthreads();
        sb[threadIdx.x] += t;
        __syncthreads();
    }
    int i = blockIdx.x * 256 + threadIdx.x;
    if (i == 0) row_start[N] = E;
    if (i >= N) return;
    int rs = pre[i] + sb[blockIdx.x] - bsums[blockIdx.x];  // exclusive block prefix
    row_start[i] = rs;
    int r = i / RS, idx = i - r * RS;
    const unsigned short* pi = parts + ((size_t)(r * 2 + 1) * NCHUNK) * RS + idx;
    int run = rs;
#pragma unroll
    for (int c = 0; c < NCHUNK; c++) {
        cpre[(size_t)c * N + i] = run;
        run += pi[(size_t)c * RS];
    }
}

// CSR scatter: range x chunk blocks, LDS cursors seeded from cpre. No global atomics.
__global__ __launch_bounds__(256) void scatter8_kernel(const int* __restrict__ src,
                                                       const int* __restrict__ dst,
                                                       const float* __restrict__ norm_out,
                                                       const int* __restrict__ cpre,
                                                       int2* __restrict__ edge2,
                                                       int E, int N, int RS, int ecpc) {
    extern __shared__ int cur[];          // RS ints
    int r = blockIdx.x >> 6, c = blockIdx.x & 63;
    int lo = r * RS;
    int len = min(RS, N - lo);
    for (int i = threadIdx.x; i < len; i += 256)
        cur[i] = cpre[(size_t)c * N + lo + i];
    __syncthreads();
    int e0 = c * ecpc, e1 = min(e0 + ecpc, E);
    for (int e = e0 + threadIdx.x; e < e1; e += 256) {
        int d = dst[e] - lo;
        if ((unsigned)d < (unsigned)len) {
            int s = src[e];
            int p = atomicAdd(&cur[d], 1);
            edge2[p] = make_int2(s, __float_as_int(norm_out[s]));
        }
    }
}

// ---------------- low-contention counting sort by deg_in ----------------
__global__ void histblk_kernel(const int* __restrict__ deg, int* __restrict__ hb,
                               int N, int nb) {
    __shared__ int h[256];
    h[threadIdx.x] = 0;
    __syncthreads();
    int i = blockIdx.x * 256 + threadIdx.x;
    if (i < N) atomicAdd(&h[min(deg[i], 255)], 1);
    __syncthreads();
    hb[threadIdx.x * nb + blockIdx.x] = h[threadIdx.x];
}

// r15 fused: scanB2 (in-LDS over raw bsums2) + place2.
__global__ void place2B_kernel(const int* __restrict__ deg, const int* __restrict__ hpre,
                               const int* __restrict__ bsums2, int* __restrict__ order,
                               int N, int nb, int nb2) {
    __shared__ int sc[256];
    __shared__ int cur[256];
    int v = (threadIdx.x < nb2) ? bsums2[threadIdx.x] : 0;
    sc[threadIdx.x] = v;
    __syncthreads();
    for (int off = 1; off < 256; off <<= 1) {
        int t = (threadIdx.x >= off) ? sc[threadIdx.x - off] : 0;
        __syncthreads();
        sc[threadIdx.x] += t;
        __syncthreads();
    }
    int idx = threadIdx.x * nb + blockIdx.x;
    int blk = idx >> 8;
    cur[threadIdx.x] = hpre[idx] + sc[blk] - bsums2[blk];  // exclusive prefix
    __syncthreads();
    int i = blockIdx.x * 256 + threadIdx.x;
    if (i < N) {
        int b = min(deg[i], 255);
        int p = atomicAdd(&cur[b], 1);
        order[p] = i;
    }
}

// ---------------- bf16 split (trunc/residual, hot path) ----------------
__device__ __forceinline__ void cvt8(const float f[8], bf16x8_t& ah, bf16x8_t& al) {
    union { unsigned int u[4]; bf16x8_t v; } H, L;
#pragma unroll
    for (int i = 0; i < 4; i++) {
        float v0 = f[2 * i], v1 = f[2 * i + 1];
        unsigned int b0 = __float_as_uint(v0);
        unsigned int b1 = __float_as_uint(v1);
        unsigned int m0 = b0 & 0xFFFF0000u;
        unsigned int m1 = b1 & 0xFFFF0000u;
        float r0 = v0 - __uint_as_float(m0);
        float r1 = v1 - __uint_as_float(m1);
        H.u[i] = (b0 >> 16) | m1;
        L.u[i] = (__float_as_uint(r0) >> 16) | (__float_as_uint(r1) & 0xFFFF0000u);
    }
    ah = H.v; al = L.v;
}

#define GBK 32

__device__ __forceinline__ void gload_lds16(const void* g, void* l) {
    __builtin_amdgcn_global_load_lds(
        (const __attribute__((address_space(1))) unsigned int*)g,
        (__attribute__((address_space(3))) unsigned int*)l, 16, 0, 0);
}

// ---------------- async-LDS-B bf16x3 MFMA GEMM (r13-exact, FROZEN) ----------------
// BM=64, GBK=32, depth-2 A prefetch. Three structural probes (occupancy,
// prefetch depth, K-step widening) all failed to beat ~67us -> frozen.
__global__ __launch_bounds__(256, 6) void gemm_mfma(const void* __restrict__ Av,
                                                    const unsigned short* __restrict__ Bth,
                                                    const unsigned short* __restrict__ Btl,
                                                    _Float16* __restrict__ C16,
                                                    const int* __restrict__ ipermArr,
                                                    int M, int K, int KP) {
    // [buf][part][row][slot][8 halfs] = 2*2*96*4*8 ush = 24576 B
    __shared__ alignas(16) unsigned short Bs[2][2][96][4][8];
    int tid = threadIdx.x;
    int wid = tid >> 6, lane = tid & 63;
    int q = lane >> 4, mn = lane & 15;
    int row0 = blockIdx.x * 64 + wid * 16;
    int arow = min(row0 + mn, M - 1);   // clamp (no predication): uniform VMEM count
    int nk = (K + GBK - 1) / GBK;

    const float* A32 = (const float*)Av;

    const unsigned short* gsrc[3];
    int lbase[3];
#pragma unroll
    for (int i = 0; i < 3; i++) {
        int c = wid * 192 + i * 64 + lane;
        int part = (c >= 384) ? 1 : 0;
        int rem = c - part * 384;
        int row = rem >> 2, slot = rem & 3;
        int kc = slot ^ ((row >> 1) & 3);
        gsrc[i] = (part ? Btl : Bth) + (size_t)row * KP + kc * 8;
        lbase[i] = (wid * 192 + i * 64) * 8;   // wave-uniform chunk-linear dest
    }

    auto stage = [&](int t, int buf) {
#pragma unroll
        for (int i = 0; i < 3; i++)
            gload_lds16(gsrc[i] + (size_t)t * GBK, &Bs[buf][0][0][0][0] + lbase[i]);
    };

    auto loadA = [&](int t, float* f) {
        int gk = t * GBK + q * 8;
        if (gk + 8 <= K) {
            float4 v0 = *(const float4*)(A32 + (size_t)arow * K + gk);
            float4 v1 = *(const float4*)(A32 + (size_t)arow * K + gk + 4);
            f[0] = v0.x; f[1] = v0.y; f[2] = v0.z; f[3] = v0.w;
            f[4] = v1.x; f[5] = v1.y; f[6] = v1.z; f[7] = v1.w;
        } else {
#pragma unroll
            for (int c = 0; c < 8; c++)
                f[c] = (gk + c < K) ? A32[(size_t)arow * K + gk + c] : 0.f;
        }
    };

    f32x4_t acc[6] = {};
    int slotR = q ^ ((mn >> 1) & 3);

    auto body = [&](int t, float (&cur)[8]) {
        int tn1 = (t + 1 < nk) ? t + 1 : nk - 1;   // clamped: uniform issue count
        stage(tn1, (t + 1) & 1);
        asm volatile("s_waitcnt vmcnt(5)" ::: "memory");
        __builtin_amdgcn_sched_barrier(0);
        __builtin_amdgcn_s_barrier();

        bf16x8_t ah, al;
        cvt8(cur, ah, al);                         // consume A(t)
        int tn2 = (t + 2 < nk) ? t + 2 : nk - 1;
        loadA(tn2, cur);                           // A(t+2) into freed regs

        const unsigned short* bp = &Bs[t & 1][0][0][0][0] + mn * 32 + slotR * 8;
#pragma unroll
        for (int ct = 0; ct < 6; ct++) {
            bf16x8_t bh = *(const bf16x8_t*)(bp + ct * 512);
            bf16x8_t bl = *(const bf16x8_t*)(bp + 3072 + ct * 512);
            acc[ct] = __builtin_amdgcn_mfma_f32_16x16x32_bf16(ah, bh, acc[ct], 0, 0, 0);
            acc[ct] = __builtin_amdgcn_mfma_f32_16x16x32_bf16(ah, bl, acc[ct], 0, 0, 0);
            acc[ct] = __builtin_amdgcn_mfma_f32_16x16x32_bf16(al, bh, acc[ct], 0, 0, 0);
        }
        // all reads of buf[t&1] done before anyone stages into it next iter
        asm volatile("s_waitcnt lgkmcnt(0)" ::: "memory");
        __builtin_amdgcn_sched_barrier(0);
        __builtin_amdgcn_s_barrier();
    };

    float f0[8], f1[8];
    stage(0, 0);
    loadA(0, f0);
    loadA((1 < nk) ? 1 : nk - 1, f1);

    for (int t0 = 0; t0 < nk; t0 += 2) {
        body(t0, f0);
        if (t0 + 1 < nk) body(t0 + 1, f1);   // uniform cond (nk block-uniform)
    }

    // drain outstanding VMEM (incl. LDS-destined staging loads) before exit
    asm volatile("s_waitcnt vmcnt(0)" ::: "memory");
    __builtin_amdgcn_sched_barrier(0);

#pragma unroll
    for (int reg = 0; reg < 4; reg++) {
        int gr = row0 + q * 4 + reg;
        if (gr < M) {
            int ip = ipermArr[gr];
#pragma unroll
            for (int ct = 0; ct < 6; ct++) {
                _Float16 v = (_Float16)acc[ct][reg];
                C16[(size_t)gr * 192 + ct * 16 + mn] = v;        // ypair[gr][0]
                C16[(size_t)ip * 192 + 96 + ct * 16 + mn] = v;   // ypair[iperm[gr]][1]
            }
        }
    }
}

// ---------------- gemm_small: K=96 whole-B-in-LDS, single-barrier (r10, passed) ----------------
__global__ __launch_bounds__(256, 4) void gemm_small(const _Float16* __restrict__ A16,
                                                     const unsigned short* __restrict__ Bth,
                                                     const unsigned short* __restrict__ Btl,
                                                     _Float16* __restrict__ C16,
                                                     int M) {
    __shared__ alignas(16) unsigned short Bs[3][2][96][4][8];   // 36864 B
    const int K = 96;
    int tid = threadIdx.x;
    int wid = tid >> 6, lane = tid & 63;
    int q = lane >> 4, mn = lane & 15;
    int row0 = blockIdx.x * 64 + wid * 16;
    int arow = min(row0 + mn, M - 1);

    const unsigned short* gsrc[3];
    int lbase[3];
#pragma unroll
    for (int i = 0; i < 3; i++) {
        int c = wid * 192 + i * 64 + lane;
        int part = (c >= 384) ? 1 : 0;
        int rem = c - part * 384;
        int row = rem >> 2, slot = rem & 3;
        int kc = slot ^ ((row >> 1) & 3);
        gsrc[i] = (part ? Btl : Bth) + (size_t)row * K + kc * 8;
        lbase[i] = (wid * 192 + i * 64) * 8;
    }

#pragma unroll
    for (int t = 0; t < 3; t++)
#pragma unroll
        for (int i = 0; i < 3; i++)
            gload_lds16(gsrc[i] + (size_t)t * GBK, &Bs[t][0][0][0][0] + lbase[i]);

    uint4 ra0 = *(const uint4*)(A16 + (size_t)arow * K + 0 * GBK + q * 8);
    uint4 ra1 = *(const uint4*)(A16 + (size_t)arow * K + 1 * GBK + q * 8);
    uint4 ra2 = *(const uint4*)(A16 + (size_t)arow * K + 2 * GBK + q * 8);

    asm volatile("s_waitcnt vmcnt(0)" ::: "memory");
    __builtin_amdgcn_sched_barrier(0);
    __builtin_amdgcn_s_barrier();

    f32x4_t acc[6] = {};
    int slotR = q ^ ((mn >> 1) & 3);

    auto step = [&](int t, const uint4& raw) {
        float f[8];
        const _Float16* hp = (const _Float16*)&raw;
#pragma unroll
        for (int c = 0; c < 8; c++) f[c] = (float)hp[c];
        bf16x8_t ah, al;
        cvt8(f, ah, al);
        const unsigned short* bp = &Bs[t][0][0][0][0] + mn * 32 + slotR * 8;
#pragma unroll
        for (int ct = 0; ct < 6; ct++) {
            bf16x8_t bh = *(const bf16x8_t*)(bp + ct * 512);
            bf16x8_t bl = *(const bf16x8_t*)(bp + 3072 + ct * 512);
            acc[ct] = __builtin_amdgcn_mfma_f32_16x16x32_bf16(ah, bh, acc[ct], 0, 0, 0);
            acc[ct] = __builtin_amdgcn_mfma_f32_16x16x32_bf16(ah, bl, acc[ct], 0, 0, 0);
            acc[ct] = __builtin_amdgcn_mfma_f32_16x16x32_bf16(al, bh, acc[ct], 0, 0, 0);
        }
    };

    step(0, ra0);
    step(1, ra1);
    step(2, ra2);

#pragma unroll
    for (int reg = 0; reg < 4; reg++) {
        int gr = row0 + q * 4 + reg;
        if (gr < M) {
#pragma unroll
            for (int ct = 0; ct < 6; ct++)
                C16[(size_t)gr * H96 + ct * 16 + mn] = (_Float16)acc[ct][reg];
        }
    }
}

// ---------------- helpers ----------------
__device__ __forceinline__ void fmah8(float4& a, float4& b, float s, half8_t v) {
    a.x = fmaf(s, (float)v[0], a.x); a.y = fmaf(s, (float)v[1], a.y);
    a.z = fmaf(s, (float)v[2], a.z); a.w = fmaf(s, (float)v[3], a.w);
    b.x = fmaf(s, (float)v[4], b.x); b.y = fmaf(s, (float)v[5], b.y);
    b.z = fmaf(s, (float)v[6], b.z); b.w = fmaf(s, (float)v[7], b.w);
}

__device__ __forceinline__ float4 prelu4(float4 acc, float ni, float4 b, float4 a) {
    float4 h;
    h.x = fmaf(acc.x, ni, b.x); h.x = (h.x >= 0.f) ? h.x : a.x * h.x;
    h.y = fmaf(acc.y, ni, b.y); h.y = (h.y >= 0.f) ? h.y : a.y * h.y;
    h.z = fmaf(acc.z, ni, b.z); h.z = (h.z >= 0.f) ? h.z : a.z * h.z;
    h.w = fmaf(acc.w, ni, b.w); h.w = (h.w >= 0.f) ? h.w : a.w * h.w;
    return h;
}

// ---------------- layer-1 dual-view SpMM over PAIRED fp16 table ----------------
__global__ __launch_bounds__(384) void spmm1_dual(
        const half8_t* __restrict__ yp, const int* __restrict__ row_start,
        const int2* __restrict__ edge2, const int* __restrict__ order,
        const float* __restrict__ norm_out, const float* __restrict__ norm_in,
        const float* __restrict__ b1, const float* __restrict__ a1,
        half8_t* __restrict__ hpair, int N) {
    int g = blockIdx.x * 32 + threadIdx.y;
    if (g >= N) return;
    int d = order[g];
    int tx = threadIdx.x;
    int beg = row_start[d], end = row_start[d + 1];
    const half8_t* yt = yp + tx;
    float4 a1a = {0,0,0,0}, a1b = {0,0,0,0}, a2a = {0,0,0,0}, a2b = {0,0,0,0};
    int j = beg;
    for (; j + 8 <= end; j += 8) {
        int2 e[8];
#pragma unroll
        for (int q = 0; q < 8; q++) e[q] = edge2[j + q];
        half8_t u[8], w[8];
#pragma unroll
        for (int q = 0; q < 8; q++) u[q] = yt[(size_t)e[q].x * 24];
#pragma unroll
        for (int q = 0; q < 8; q++) w[q] = yt[(size_t)e[q].x * 24 + 12];
#pragma unroll
        for (int q = 0; q < 8; q++) {
            float n = __int_as_float(e[q].y);
            fmah8(a1a, a1b, n, u[q]);
            fmah8(a2a, a2b, n, w[q]);
        }
    }
    for (; j < end; j++) {
        int2 e = edge2[j];
        float n = __int_as_float(e.y);
        fmah8(a1a, a1b, n, yt[(size_t)e.x * 24]);
        fmah8(a2a, a2b, n, yt[(size_t)e.x * 24 + 12]);
    }
    float ni = norm_in[d], no = norm_out[d];
    float4 bb0 = ((const float4*)b1)[tx * 2], bb1 = ((const float4*)b1)[tx * 2 + 1];
    float4 aa0 = ((const float4*)a1)[tx * 2], aa1 = ((const float4*)a1)[tx * 2 + 1];
    float4 r1a = prelu4(a1a, ni, bb0, aa0), r1b = prelu4(a1b, ni, bb1, aa1);
    float4 r2a = prelu4(a2a, ni, bb0, aa0), r2b = prelu4(a2b, ni, bb1, aa1);
    half8_t o1, o2;
    o1[0] = (_Float16)(r1a.x * no); o1[1] = (_Float16)(r1a.y * no);
    o1[2] = (_Float16)(r1a.z * no); o1[3] = (_Float16)(r1a.w * no);
    o1[4] = (_Float16)(r1b.x * no); o1[5] = (_Float16)(r1b.y * no);
    o1[6] = (_Float16)(r1b.z * no); o1[7] = (_Float16)(r1b.w * no);
    o2[0] = (_Float16)(r2a.x * no); o2[1] = (_Float16)(r2a.y * no);
    o2[2] = (_Float16)(r2a.z * no); o2[3] = (_Float16)(r2a.w * no);
    o2[4] = (_Float16)(r2b.x * no); o2[5] = (_Float16)(r2b.y * no);
    o2[6] = (_Float16)(r2b.z * no); o2[7] = (_Float16)(r2b.w * no);
    hpair[(size_t)d * 24 + tx] = o1;
    hpair[(size_t)d * 24 + 12 + tx] = o2;
}

// ---------------- layer-2 dual-view SpMM over node-interleaved t table ----------------
__global__ __launch_bounds__(384) void spmm2_dual(
        const half8_t* __restrict__ th,
        const int* __restrict__ row_start, const int2* __restrict__ edge2,
        const int* __restrict__ order, const float* __restrict__ norm_in,
        const float* __restrict__ b2, const float* __restrict__ a2,
        const float* __restrict__ wsum, const float* __restrict__ bsum,
        float* __restrict__ outp, int N) {
    int g = blockIdx.x * 32 + threadIdx.y;
    int tx = threadIdx.x;
    int ty = threadIdx.y;
    bool valid = (g < N);
    int d = valid ? order[g] : 0;
    int beg = 0, end = 0;
    if (valid) { beg = row_start[d]; end = row_start[d + 1]; }
    const half8_t* t1 = th + tx;
    float4 a1a = {0,0,0,0}, a1b = {0,0,0,0}, a2a = {0,0,0,0}, a2b = {0,0,0,0};
    int j = beg;
    for (; j + 8 <= end; j += 8) {
        int s[8];
#pragma unroll
        for (int q = 0; q < 8; q++) s[q] = edge2[j + q].x;
        half8_t u[8], w[8];
#pragma unroll
        for (int q = 0; q < 8; q++) u[q] = t1[(size_t)s[q] * 24];
#pragma unroll
        for (int q = 0; q < 8; q++) w[q] = t1[(size_t)s[q] * 24 + 12];
#pragma unroll
        for (int q = 0; q < 8; q++) {
            fmah8(a1a, a1b, 1.f, u[q]);
            fmah8(a2a, a2b, 1.f, w[q]);
        }
    }
    for (; j < end; j++) {
        int s = edge2[j].x;
        fmah8(a1a, a1b, 1.f, t1[(size_t)s * 24]);
        fmah8(a2a, a2b, 1.f, t1[(size_t)s * 24 + 12]);
    }
    float ni = valid ? norm_in[d] : 0.f;
    float4 bb0 = ((const float4*)b2)[tx * 2], bb1 = ((const float4*)b2)[tx * 2 + 1];
    float4 aa0 = ((const float4*)a2)[tx * 2], aa1 = ((const float4*)a2)[tx * 2 + 1];
    float4 wv0 = ((const float4*)wsum)[tx * 2], wv1 = ((const float4*)wsum)[tx * 2 + 1];
    float4 r1a = prelu4(a1a, ni, bb0, aa0), r1b = prelu4(a1b, ni, bb1, aa1);
    float4 r2a = prelu4(a2a, ni, bb0, aa0), r2b = prelu4(a2b, ni, bb1, aa1);
    float p1 = r1a.x * wv0.x + r1a.y * wv0.y + r1a.z * wv0.z + r1a.w * wv0.w
             + r1b.x * wv1.x + r1b.y * wv1.y + r1b.z * wv1.z + r1b.w * wv1.w;
    float p2 = r2a.x * wv0.x + r2a.y * wv0.y + r2a.z * wv0.z + r2a.w * wv0.w
             + r2b.x * wv1.x + r2b.y * wv1.y + r2b.z * wv1.z + r2b.w * wv1.w;
    __shared__ float red1[32][12];
    __shared__ float red2[32][12];
    red1[ty][tx] = p1;
    red2[ty][tx] = p2;
    __syncthreads();
    if (tx == 0 && valid) {
        float s1 = 0.f, s2 = 0.f;
#pragma unroll
        for (int k = 0; k < 12; k++) { s1 += red1[ty][k]; s2 += red2[ty][k]; }
        outp[d] = s1 + bsum[0];
        outp[N + d] = s2 + bsum[0];
    }
}

extern "C" void kernel_launch(void* const* d_in, const int* in_sizes, int n_in,
                              void* d_out, int out_size, void* d_ws, size_t ws_size,
                              hipStream_t stream) {
    const float* x    = (const float*)d_in[0];
    const int*   src  = (const int*)d_in[1];
    const int*   dst  = (const int*)d_in[2];
    const int*   perm = (const int*)d_in[3];
    const float* W1   = (const float*)d_in[4];
    const float* b1   = (const float*)d_in[5];
    const float* a1   = (const float*)d_in[6];
    const float* W2   = (const float*)d_in[7];
    const float* b2   = (const float*)d_in[8];
    const float* a2   = (const float*)d_in[9];
    const float* Wm   = (const float*)d_in[10];
    const float* bm   = (const float*)d_in[11];
    float* out = (float*)d_out;

    int E = in_sizes[1];
    int N = in_sizes[3];
    int F = in_sizes[0] / N;               // 500
    int KP1 = ((F + GBK - 1) / GBK) * GBK; // 512

    size_t NP = ((size_t)N + 256) & ~(size_t)255;
    size_t EP = ((size_t)E + 255) & ~(size_t)255;
    int nb = (N + 255) / 256;
    size_t HB = ((size_t)256 * nb + 255) & ~(size_t)255;

    int* iperm     = (int*)d_ws;          // NP
    int* deg_in    = iperm + NP;          // NP
    int* pre       = deg_in + NP;         // NP
    int* row_start = pre + NP;            // NP
    int* cursor    = row_start + NP;      // NP (unused slot, kept for layout)
    int* order     = cursor + NP;         // NP
    int* bsums     = order + NP;          // 256
    int* hb        = bsums + 256;         // HB
    int* hpre      = hb + HB;             // HB
    int2* edge2    = (int2*)(hpre + HB);  // EP int2 (6.4MB)
    float* norm_out = (float*)(edge2 + EP);    // NP
    float* norm_in  = norm_out + NP;           // NP
    float* wsum     = norm_in + NP;            // 128
    float* bsum     = wsum + 128;              // 128
    unsigned short* w1th = (unsigned short*)(bsum + 128); // 96*KP1 pad 49664
    unsigned short* w1tl = w1th + 49664;
    unsigned short* w2th = w1tl + 49664;                  // 96*96 pad 9728
    unsigned short* w2tl = w2th + 9728;
    // fp16 scratch: fpA = ypair then th (aliased; ypair dead after spmm1),
    // fpB = hpair.
    _Float16* fpA = (_Float16*)(w2tl + 9728);            // N*192 + 256
    _Float16* fpB = fpA + ((size_t)N * 192 + 256);       // 2N*96 + 256
    _Float16* ypair = fpA;
    _Float16* hpair = fpB;
    _Float16* th    = fpA;

    // hist partials (12.8MB) alias fpA (19.2MB): dead after rowfinC.
    // cpre (64*N ints = 12.8MB) aliases fpB (19.2MB): dead after scatter8;
    // hpair written only later by spmm1 (same-stream ordering).
    unsigned short* parts = (unsigned short*)fpA;
    int* cpre = (int*)fpB;

    int RS = (N + NRANGE - 1) / NRANGE;                   // 6250
    int ecpc = ((E + NCHUNK - 1) / NCHUNK + 3) & ~3;      // %4==0 for int4 loads
    int wtot = 96 * KP1 + 96 * 96 + 96 + 1;
    int wblocks = (wtot + 255) / 256;
    hist2w_kernel<<<NRANGE * NCHUNK + wblocks, 256, 2 * RS * (int)sizeof(int), stream>>>(
        src, dst, parts, E, RS, ecpc,
        W1, W2, Wm, bm, w1th, w1tl, w2th, w2tl, wsum, bsum, F, KP1);
    degred_kernel<<<(N + 255) / 256, 256, 0, stream>>>(parts, perm, deg_in, iperm,
                                                       norm_out, norm_in, N, RS);

    scanA_kernel<<<nb, 256, 0, stream>>>(deg_in, pre, bsums, N);
    rowfinC_kernel<<<nb, 256, 0, stream>>>(pre, bsums, parts, row_start, cpre,
                                           N, E, RS, nb);
    scatter8_kernel<<<NRANGE * NCHUNK, 256, RS * (int)sizeof(int), stream>>>(
        src, dst, norm_out, cpre, edge2, E, N, RS, ecpc);

    histblk_kernel<<<nb, 256, 0, stream>>>(deg_in, hb, N, nb);
    int n2 = 256 * nb;
    int nb2 = (n2 + 255) / 256;
    scanA_kernel<<<nb2, 256, 0, stream>>>(hb, hpre, bsums, n2);
    place2B_kernel<<<nb, 256, 0, stream>>>(deg_in, hpre, bsums, order, N, nb, nb2);

    // ypair = fp16(x @ W1) with pair-write epilogue (A fp32), r13-frozen gemm
    gemm_mfma<<<(N + 63) / 64, 256, 0, stream>>>(x, w1th, w1tl, ypair, iperm,
                                                 N, F, KP1);

    int nsb = (N + 31) / 32;
    spmm1_dual<<<nsb, dim3(12, 32), 0, stream>>>(
        (const half8_t*)ypair, row_start, edge2, order, norm_out, norm_in,
        b1, a1, (half8_t*)hpair, N);

    // th = fp16(hpair @ W2): whole-B-in-LDS single-barrier kernel (K=96)
    gemm_small<<<(2 * N + 63) / 64, 256, 0, stream>>>(hpair, w2th, w2tl, th, 2 * N);

    spmm2_dual<<<nsb, dim3(12, 32), 0, stream>>>(
        (const half8_t*)th, row_start, edge2, order, norm_in, b2, a2,
        wsum, bsum, out, N);
}